// Round 3
// baseline (383.674 us; speedup 1.0000x reference)
//
#include <hip/hip_runtime.h>
#include <math.h>

typedef unsigned short u16;
typedef unsigned int u32;

#define KNBR 32

__device__ __forceinline__ float bf2f(u16 u) { return __uint_as_float((u32)u << 16); }
__device__ __forceinline__ float bflo(u32 u) { return __uint_as_float(u << 16); }
__device__ __forceinline__ float bfhi(u32 u) { return __uint_as_float(u & 0xffff0000u); }
__device__ __forceinline__ u16 f2bf(float f) {
    u32 u = __float_as_uint(f);
    return (u16)((u + 0x7fffu + ((u >> 16) & 1u)) >> 16);
}
__device__ __forceinline__ u32 pk2(float a, float b) {
    return (u32)f2bf(a) | ((u32)f2bf(b) << 16);
}
__device__ __forceinline__ float leaky(float v) { return v >= 0.f ? v : 0.1f * v; }
__device__ __forceinline__ float sigm(float v) { return 1.f / (1.f + expf(-v)); }

// W1: [3][131][64] fp32 (row g*8384 + c*64 + d), b1: [3][64],
// W2/W3: [3][64][64] (g*4096 + c*64 + d), b2/b3: [3][64].

// K1: P01[pl][j] (bf16) = b1[g][d] + sum_c [h|x][p][c] * W1[g][c][d],  j = g*64+d
__global__ __launch_bounds__(256) void k_gemm_p01(
    const float* __restrict__ h, const float* __restrict__ x,
    const float* __restrict__ W1f, const float* __restrict__ b1f,
    u16* __restrict__ P01, int p0)
{
    __shared__ float a_lds[64 * 132];
    int t = threadIdx.x;
    int plb = blockIdx.x * 64;          // local point base
    int pgb = p0 + plb;                 // global point base
    for (int i = 0; i < 8; ++i) {
        int id = t + i * 256;           // 0..2047
        int p = id >> 5, c4 = id & 31;
        const float* src = (c4 < 16) ? (h + (size_t)(pgb + p) * 64 + c4 * 4)
                                     : (x + (size_t)(pgb + p) * 64 + (c4 - 16) * 4);
        float4 v = *(const float4*)src;
        *(float4*)&a_lds[p * 132 + c4 * 4] = v;
    }
    __syncthreads();
    int lane = t & 63;
    int cg = t >> 6;                    // 0..3
    int gate = cg >> 1;
    int dbase = (cg & 1) * 32;
    const float* wbase = W1f + gate * 8384 + dbase;
    float acc[32];
    #pragma unroll
    for (int j = 0; j < 32; ++j) acc[j] = b1f[gate * 64 + dbase + j];
    const float4* arow = (const float4*)&a_lds[lane * 132];
    for (int c4 = 0; c4 < 32; ++c4) {
        float4 a = arow[c4];
        const float* w0 = wbase + c4 * 256;
        #pragma unroll
        for (int j = 0; j < 32; ++j) acc[j] = fmaf(a.x, w0[j], acc[j]);
        #pragma unroll
        for (int j = 0; j < 32; ++j) acc[j] = fmaf(a.y, w0[64 + j], acc[j]);
        #pragma unroll
        for (int j = 0; j < 32; ++j) acc[j] = fmaf(a.z, w0[128 + j], acc[j]);
        #pragma unroll
        for (int j = 0; j < 32; ++j) acc[j] = fmaf(a.w, w0[192 + j], acc[j]);
    }
    u16* dst = P01 + (size_t)(plb + lane) * 128 + cg * 32;
    u32 o[16];
    #pragma unroll
    for (int j = 0; j < 16; ++j) o[j] = pk2(acc[2 * j], acc[2 * j + 1]);
    #pragma unroll
    for (int q = 0; q < 4; ++q) ((uint4*)dst)[q] = *(uint4*)&o[q * 4];
}

// K2: gather + edge-proj + maxpool, gates 0,1. one wave per point, lane = channel.
__global__ __launch_bounds__(256) void k_pool01(
    const u16* __restrict__ P01, const float* __restrict__ W1f,
    const int* __restrict__ nidx, const float* __restrict__ ef,
    u16* __restrict__ Y01, int p0)
{
    int t = threadIdx.x;
    int l = t & 63;
    int wv = t >> 6;
    int pl = blockIdx.x * 4 + wv;
    int pg = p0 + pl;
    int rbase = ((pg >> 13) << 13) - p0;   // local row base of this point's batch
    float w00 = W1f[8192 + l], w01 = W1f[8256 + l], w02 = W1f[8320 + l];
    float w10 = W1f[16576 + l], w11 = W1f[16640 + l], w12 = W1f[16704 + l];
    const int* ni = nidx + (size_t)pg * KNBR;
    const float* ep = ef + (size_t)pg * KNBR * 3;
    float m0 = -1e30f, m1 = -1e30f;
    #pragma unroll 4
    for (int k = 0; k < KNBR; ++k) {
        int lr = rbase + ni[k];
        float e0 = ep[k * 3 + 0];
        float e1 = ep[k * 3 + 1];
        float e2 = ep[k * 3 + 2];
        const u16* pr = P01 + (size_t)lr * 128;
        float v0 = bf2f(pr[l])      + e0 * w00 + e1 * w01 + e2 * w02;
        float v1 = bf2f(pr[64 + l]) + e0 * w10 + e1 * w11 + e2 * w12;
        m0 = fmaxf(m0, v0);
        m1 = fmaxf(m1, v1);
    }
    Y01[(size_t)pl * 128 + l]      = f2bf(leaky(m0));
    Y01[(size_t)pl * 128 + 64 + l] = f2bf(leaky(m1));
}

// K3: 2-layer MLP gates 0,1 -> Z = sigmoid(g0) (bf16), RH = sigmoid(g1)*h (bf16)
__global__ __launch_bounds__(256) void k_mlp01(
    const u16* __restrict__ Y01,
    const float* __restrict__ W2f, const float* __restrict__ b2f,
    const float* __restrict__ W3f, const float* __restrict__ b3f,
    const float* __restrict__ h, u16* __restrict__ Z, u16* __restrict__ RH, int p0)
{
    __shared__ float a_lds[64 * 132];
    __shared__ float t_lds[64 * 132];
    int t = threadIdx.x;
    int plb = blockIdx.x * 64;
    for (int i = 0; i < 4; ++i) {
        int id = t + i * 256;           // 0..1023
        int p = id >> 4, c8 = id & 15;
        uint4 u = *(const uint4*)(Y01 + (size_t)(plb + p) * 128 + c8 * 8);
        float* d = &a_lds[p * 132 + c8 * 8];
        d[0] = bflo(u.x); d[1] = bfhi(u.x); d[2] = bflo(u.y); d[3] = bfhi(u.y);
        d[4] = bflo(u.z); d[5] = bfhi(u.z); d[6] = bflo(u.w); d[7] = bfhi(u.w);
    }
    __syncthreads();
    int lane = t & 63;
    int cg = t >> 6;
    int gate = cg >> 1, dbase = (cg & 1) * 32;
    {
        const float* wb = W2f + gate * 4096 + dbase;
        float acc[32];
        #pragma unroll
        for (int j = 0; j < 32; ++j) acc[j] = b2f[gate * 64 + dbase + j];
        const float* ar = &a_lds[lane * 132 + gate * 64];
        for (int c = 0; c < 64; ++c) {
            float a = ar[c];
            const float* w0 = wb + c * 64;
            #pragma unroll
            for (int j = 0; j < 32; ++j) acc[j] = fmaf(a, w0[j], acc[j]);
        }
        float* dst = &t_lds[lane * 132 + cg * 32];
        #pragma unroll
        for (int j = 0; j < 32; ++j) dst[j] = leaky(acc[j]);
    }
    __syncthreads();
    {
        const float* wb = W3f + gate * 4096 + dbase;
        float acc[32];
        #pragma unroll
        for (int j = 0; j < 32; ++j) acc[j] = b3f[gate * 64 + dbase + j];
        const float* tr = &t_lds[lane * 132 + gate * 64];
        for (int c = 0; c < 64; ++c) {
            float a = tr[c];
            const float* w0 = wb + c * 64;
            #pragma unroll
            for (int j = 0; j < 32; ++j) acc[j] = fmaf(a, w0[j], acc[j]);
        }
        int pl = plb + lane;
        int pg = p0 + pl;
        u32 o[16];
        if (gate == 0) {
            #pragma unroll
            for (int j = 0; j < 16; ++j) o[j] = pk2(sigm(acc[2 * j]), sigm(acc[2 * j + 1]));
            u16* dst = Z + (size_t)pl * 64 + dbase;
            #pragma unroll
            for (int q = 0; q < 4; ++q) ((uint4*)dst)[q] = *(uint4*)&o[q * 4];
        } else {
            const float* hp = h + (size_t)pg * 64 + dbase;
            float rh[32];
            #pragma unroll
            for (int j = 0; j < 32; ++j) rh[j] = sigm(acc[j]) * hp[j];
            #pragma unroll
            for (int j = 0; j < 16; ++j) o[j] = pk2(rh[2 * j], rh[2 * j + 1]);
            u16* dst = RH + (size_t)pl * 64 + dbase;
            #pragma unroll
            for (int q = 0; q < 4; ++q) ((uint4*)dst)[q] = *(uint4*)&o[q * 4];
        }
    }
}

// K4: P2[pl][d] (bf16) = b1[2][d] + sum_c [RH|x][p][c] * W1[2][c][d]
__global__ __launch_bounds__(256) void k_gemm_p2(
    const u16* __restrict__ RH, const float* __restrict__ x,
    const float* __restrict__ W1f, const float* __restrict__ b1f,
    u16* __restrict__ P2, int p0)
{
    __shared__ float a_lds[64 * 132];
    int t = threadIdx.x;
    int plb = blockIdx.x * 64;
    int pgb = p0 + plb;
    for (int i = 0; i < 2; ++i) {       // RH half (bf16, local rows)
        int id = t + i * 256;           // 0..511
        int p = id >> 3, c8 = id & 7;
        uint4 u = *(const uint4*)(RH + (size_t)(plb + p) * 64 + c8 * 8);
        float* d = &a_lds[p * 132 + c8 * 8];
        d[0] = bflo(u.x); d[1] = bfhi(u.x); d[2] = bflo(u.y); d[3] = bfhi(u.y);
        d[4] = bflo(u.z); d[5] = bfhi(u.z); d[6] = bflo(u.w); d[7] = bfhi(u.w);
    }
    for (int i = 0; i < 4; ++i) {       // x half (fp32, global rows)
        int id = t + i * 256;           // 0..1023
        int p = id >> 4, c4 = id & 15;
        float4 v = *(const float4*)(x + (size_t)(pgb + p) * 64 + c4 * 4);
        *(float4*)&a_lds[p * 132 + 64 + c4 * 4] = v;
    }
    __syncthreads();
    int lane = t & 63;
    int cg = t >> 6;
    int dbase = cg * 16;
    const float* wbase = W1f + 2 * 8384 + dbase;
    float acc[16];
    #pragma unroll
    for (int j = 0; j < 16; ++j) acc[j] = b1f[128 + dbase + j];
    const float4* arow = (const float4*)&a_lds[lane * 132];
    for (int c4 = 0; c4 < 32; ++c4) {
        float4 a = arow[c4];
        const float* w0 = wbase + c4 * 256;
        #pragma unroll
        for (int j = 0; j < 16; ++j) acc[j] = fmaf(a.x, w0[j], acc[j]);
        #pragma unroll
        for (int j = 0; j < 16; ++j) acc[j] = fmaf(a.y, w0[64 + j], acc[j]);
        #pragma unroll
        for (int j = 0; j < 16; ++j) acc[j] = fmaf(a.z, w0[128 + j], acc[j]);
        #pragma unroll
        for (int j = 0; j < 16; ++j) acc[j] = fmaf(a.w, w0[192 + j], acc[j]);
    }
    u16* dst = P2 + (size_t)(plb + lane) * 64 + dbase;
    u32 o[8];
    #pragma unroll
    for (int j = 0; j < 8; ++j) o[j] = pk2(acc[2 * j], acc[2 * j + 1]);
    #pragma unroll
    for (int q = 0; q < 2; ++q) ((uint4*)dst)[q] = *(uint4*)&o[q * 4];
}

// K5: gather + edge + maxpool, gate 2
__global__ __launch_bounds__(256) void k_pool2(
    const u16* __restrict__ P2, const float* __restrict__ W1f,
    const int* __restrict__ nidx, const float* __restrict__ ef,
    u16* __restrict__ Y2, int p0)
{
    int t = threadIdx.x;
    int l = t & 63;
    int wv = t >> 6;
    int pl = blockIdx.x * 4 + wv;
    int pg = p0 + pl;
    int rbase = ((pg >> 13) << 13) - p0;
    const float* W = W1f + 2 * 8384;
    float w0 = W[8192 + l], w1 = W[8256 + l], w2 = W[8320 + l];
    const int* ni = nidx + (size_t)pg * KNBR;
    const float* ep = ef + (size_t)pg * KNBR * 3;
    float m = -1e30f;
    #pragma unroll 4
    for (int k = 0; k < KNBR; ++k) {
        int lr = rbase + ni[k];
        float e0 = ep[k * 3 + 0];
        float e1 = ep[k * 3 + 1];
        float e2 = ep[k * 3 + 2];
        float v = bf2f(P2[(size_t)lr * 64 + l]) + e0 * w0 + e1 * w1 + e2 * w2;
        m = fmaxf(m, v);
    }
    Y2[(size_t)pl * 64 + l] = f2bf(leaky(m));
}

// K6: MLP gate 2 -> q = tanh, out = (1-z)*h + z*q  (fp32 out)
__global__ __launch_bounds__(256) void k_mlp2(
    const u16* __restrict__ Y2,
    const float* __restrict__ W2f, const float* __restrict__ b2f,
    const float* __restrict__ W3f, const float* __restrict__ b3f,
    const float* __restrict__ h, const u16* __restrict__ Z,
    float* __restrict__ out, int p0)
{
    __shared__ float a_lds[64 * 68];
    __shared__ float t_lds[64 * 68];
    int t = threadIdx.x;
    int plb = blockIdx.x * 64;
    for (int i = 0; i < 2; ++i) {
        int id = t + i * 256;           // 0..511
        int p = id >> 3, c8 = id & 7;
        uint4 u = *(const uint4*)(Y2 + (size_t)(plb + p) * 64 + c8 * 8);
        float* d = &a_lds[p * 68 + c8 * 8];
        d[0] = bflo(u.x); d[1] = bfhi(u.x); d[2] = bflo(u.y); d[3] = bfhi(u.y);
        d[4] = bflo(u.z); d[5] = bfhi(u.z); d[6] = bflo(u.w); d[7] = bfhi(u.w);
    }
    __syncthreads();
    int lane = t & 63;
    int cg = t >> 6;
    int dbase = cg * 16;
    float acc[16];
    {
        const float* wb = W2f + 2 * 4096 + dbase;
        #pragma unroll
        for (int j = 0; j < 16; ++j) acc[j] = b2f[128 + dbase + j];
        const float* ar = &a_lds[lane * 68];
        for (int c = 0; c < 64; ++c) {
            float a = ar[c];
            const float* w0 = wb + c * 64;
            #pragma unroll
            for (int j = 0; j < 16; ++j) acc[j] = fmaf(a, w0[j], acc[j]);
        }
        float* td = &t_lds[lane * 68 + dbase];
        #pragma unroll
        for (int j = 0; j < 16; ++j) td[j] = leaky(acc[j]);
    }
    __syncthreads();
    {
        const float* wb = W3f + 2 * 4096 + dbase;
        #pragma unroll
        for (int j = 0; j < 16; ++j) acc[j] = b3f[128 + dbase + j];
        const float* tr = &t_lds[lane * 68];
        for (int c = 0; c < 64; ++c) {
            float a = tr[c];
            const float* w0 = wb + c * 64;
            #pragma unroll
            for (int j = 0; j < 16; ++j) acc[j] = fmaf(a, w0[j], acc[j]);
        }
        int pl = plb + lane;
        int pg = p0 + pl;
        const float* hp = h + (size_t)pg * 64 + dbase;
        const u16* zp = Z + (size_t)pl * 64 + dbase;
        float* op = out + (size_t)pg * 64 + dbase;
        float o[16];
        #pragma unroll
        for (int j = 0; j < 16; ++j) {
            float q = tanhf(acc[j]);
            float z = bf2f(zp[j]);
            o[j] = (1.f - z) * hp[j] + z * q;
        }
        #pragma unroll
        for (int q4 = 0; q4 < 4; ++q4)
            *(float4*)&op[q4 * 4] = make_float4(o[q4*4], o[q4*4+1], o[q4*4+2], o[q4*4+3]);
    }
}

extern "C" void kernel_launch(void* const* d_in, const int* in_sizes, int n_in,
                              void* d_out, int out_size, void* d_ws, size_t ws_size,
                              hipStream_t stream)
{
    const float* h  = (const float*)d_in[0];
    const float* x  = (const float*)d_in[1];
    // d_in[2] = c (unused by the reference)
    const float* W1 = (const float*)d_in[3];
    const float* b1 = (const float*)d_in[4];
    const float* W2 = (const float*)d_in[5];
    const float* b2 = (const float*)d_in[6];
    const float* W3 = (const float*)d_in[7];
    const float* b3 = (const float*)d_in[8];
    const int* nidx = (const int*)d_in[9];
    const float* ef = (const float*)d_in[10];
    float* out = (float*)d_out;

    char* wsb = (char*)d_ws;
    // pass size: full (32768 points, needs 32768*512 B = 16.78 MB)
    // or per-batch fallback (8192 points/pass, needs 4.2 MB)
    size_t PN = (ws_size >= 32768ull * 512ull) ? 32768 : 8192;
    int passes = (int)(32768 / PN);

    u16* P01 = (u16*)wsb;                       // [PN][128] bf16
    u16* Y01 = (u16*)(wsb + PN * 256);          // [PN][128] bf16
    u16* Z   = P01;                             // alias (P01 dead after K2)
    u16* RH  = (u16*)(wsb + PN * 128);          // alias P01 upper half
    u16* P2  = Y01;                             // alias (Y01 dead after K3)
    u16* Y2  = (u16*)((char*)Y01 + PN * 128);   // alias Y01 upper half

    for (int s = 0; s < passes; ++s) {
        int p0 = (int)(s * PN);
        dim3 gM((unsigned)(PN / 64));
        dim3 gP((unsigned)(PN / 4));
        k_gemm_p01<<<gM, 256, 0, stream>>>(h, x, W1, b1, P01, p0);
        k_pool01 <<<gP, 256, 0, stream>>>(P01, W1, nidx, ef, Y01, p0);
        k_mlp01  <<<gM, 256, 0, stream>>>(Y01, W2, b2, W3, b3, h, Z, RH, p0);
        k_gemm_p2<<<gM, 256, 0, stream>>>(RH, x, W1, b1, P2, p0);
        k_pool2  <<<gP, 256, 0, stream>>>(P2, W1, nidx, ef, Y2, p0);
        k_mlp2   <<<gM, 256, 0, stream>>>(Y2, W2, b2, W3, b3, h, Z, out, p0);
    }
}

// Round 4
// 229.132 us; speedup vs baseline: 1.6745x; 1.6745x over previous
//
#include <hip/hip_runtime.h>
#include <math.h>

typedef unsigned short u16;
typedef unsigned int u32;

#define KNBR 32

__device__ __forceinline__ float bf2f(u16 u) { return __uint_as_float((u32)u << 16); }
__device__ __forceinline__ float bflo(u32 u) { return __uint_as_float(u << 16); }
__device__ __forceinline__ float bfhi(u32 u) { return __uint_as_float(u & 0xffff0000u); }
__device__ __forceinline__ u16 f2bf(float f) {
    u32 u = __float_as_uint(f);
    return (u16)((u + 0x7fffu + ((u >> 16) & 1u)) >> 16);
}
__device__ __forceinline__ u32 pk2(float a, float b) {
    return (u32)f2bf(a) | ((u32)f2bf(b) << 16);
}
__device__ __forceinline__ float leaky(float v) { return v >= 0.f ? v : 0.1f * v; }
__device__ __forceinline__ float sigm(float v) { return 1.f / (1.f + expf(-v)); }

// W1: [3][131][64] fp32 (g*8384 + c*64 + d), b1: [3][64],
// W2/W3: [3][64][64] (g*4096 + c*64 + d), b2/b3: [3][64].
// P01: u32 rows of 64 (channel d holds pk2(gate0, gate1)).

// K1: both gates of layer-1 pre-activation for all points.
__global__ __launch_bounds__(256) void k_gemm_p01(
    const float* __restrict__ h, const float* __restrict__ x,
    const float* __restrict__ W1f, const float* __restrict__ b1f,
    u32* __restrict__ P01, int p0)
{
    __shared__ float a_lds[64 * 132];
    int t = threadIdx.x;
    int plb = blockIdx.x * 64;
    int pgb = p0 + plb;
    for (int i = 0; i < 8; ++i) {
        int id = t + i * 256;           // 0..2047
        int p = id >> 5, c4 = id & 31;
        const float* src = (c4 < 16) ? (h + (size_t)(pgb + p) * 64 + c4 * 4)
                                     : (x + (size_t)(pgb + p) * 64 + (c4 - 16) * 4);
        float4 v = *(const float4*)src;
        *(float4*)&a_lds[p * 132 + c4 * 4] = v;
    }
    __syncthreads();
    int lane = t & 63;
    int cg = __builtin_amdgcn_readfirstlane(threadIdx.x >> 6);   // 0..3, wave-uniform
    int dbase = cg * 16;                 // 16 channels, both gates
    const float* wg0 = W1f + dbase;             // gate 0
    const float* wg1 = W1f + 8384 + dbase;      // gate 1
    float acc0[16], acc1[16];
    #pragma unroll
    for (int j = 0; j < 16; ++j) { acc0[j] = b1f[dbase + j]; acc1[j] = b1f[64 + dbase + j]; }
    const float4* arow = (const float4*)&a_lds[lane * 132];
    for (int c4 = 0; c4 < 32; ++c4) {
        float4 a = arow[c4];
        const float* wa = wg0 + c4 * 256;
        const float* wb = wg1 + c4 * 256;
        #pragma unroll
        for (int j = 0; j < 16; ++j) acc0[j] = fmaf(a.x, wa[j], acc0[j]);
        #pragma unroll
        for (int j = 0; j < 16; ++j) acc0[j] = fmaf(a.y, wa[64 + j], acc0[j]);
        #pragma unroll
        for (int j = 0; j < 16; ++j) acc0[j] = fmaf(a.z, wa[128 + j], acc0[j]);
        #pragma unroll
        for (int j = 0; j < 16; ++j) acc0[j] = fmaf(a.w, wa[192 + j], acc0[j]);
        #pragma unroll
        for (int j = 0; j < 16; ++j) acc1[j] = fmaf(a.x, wb[j], acc1[j]);
        #pragma unroll
        for (int j = 0; j < 16; ++j) acc1[j] = fmaf(a.y, wb[64 + j], acc1[j]);
        #pragma unroll
        for (int j = 0; j < 16; ++j) acc1[j] = fmaf(a.z, wb[128 + j], acc1[j]);
        #pragma unroll
        for (int j = 0; j < 16; ++j) acc1[j] = fmaf(a.w, wb[192 + j], acc1[j]);
    }
    u32* dst = P01 + (size_t)(plb + lane) * 64 + dbase;
    u32 o[16];
    #pragma unroll
    for (int j = 0; j < 16; ++j) o[j] = pk2(acc0[j], acc1[j]);
    #pragma unroll
    for (int q = 0; q < 4; ++q) ((uint4*)dst)[q] = *(uint4*)&o[q * 4];
}

// K2: gather + edge-proj + maxpool, gates 0,1. one wave/point, lane = channel.
__global__ __launch_bounds__(256) void k_pool01(
    const u32* __restrict__ P01, const float* __restrict__ W1f,
    const int* __restrict__ nidx, const float* __restrict__ ef,
    u16* __restrict__ Y01, int p0)
{
    int t = threadIdx.x;
    int l = t & 63;
    int wv = __builtin_amdgcn_readfirstlane(threadIdx.x >> 6);
    int pl = blockIdx.x * 4 + wv;
    int pg = p0 + pl;
    int rbase = ((pg >> 13) << 13) - p0;
    float w00 = W1f[8192 + l], w01 = W1f[8256 + l], w02 = W1f[8320 + l];
    float w10 = W1f[16576 + l], w11 = W1f[16640 + l], w12 = W1f[16704 + l];
    const int* ni = nidx + (size_t)pg * KNBR;
    const float* ep = ef + (size_t)pg * KNBR * 3;
    float m0 = -1e30f, m1 = -1e30f;
    #pragma unroll 8
    for (int k = 0; k < KNBR; ++k) {
        int lr = rbase + ni[k];
        float e0 = ep[k * 3 + 0];
        float e1 = ep[k * 3 + 1];
        float e2 = ep[k * 3 + 2];
        u32 g = P01[(size_t)lr * 64 + l];
        float v0 = bflo(g) + e0 * w00 + e1 * w01 + e2 * w02;
        float v1 = bfhi(g) + e0 * w10 + e1 * w11 + e2 * w12;
        m0 = fmaxf(m0, v0);
        m1 = fmaxf(m1, v1);
    }
    Y01[(size_t)pl * 128 + l]      = f2bf(leaky(m0));
    Y01[(size_t)pl * 128 + 64 + l] = f2bf(leaky(m1));
}

// K3: 2-layer MLP gates 0,1 -> Z = sigmoid(g0) (bf16), RH = sigmoid(g1)*h (bf16)
__global__ __launch_bounds__(256) void k_mlp01(
    const u16* __restrict__ Y01,
    const float* __restrict__ W2f, const float* __restrict__ b2f,
    const float* __restrict__ W3f, const float* __restrict__ b3f,
    const float* __restrict__ h, u16* __restrict__ Z, u16* __restrict__ RH, int p0)
{
    __shared__ float a_lds[64 * 133];
    __shared__ float t_lds[64 * 133];
    int t = threadIdx.x;
    int plb = blockIdx.x * 64;
    for (int i = 0; i < 4; ++i) {
        int id = t + i * 256;           // 0..1023
        int p = id >> 4, c8 = id & 15;
        uint4 u = *(const uint4*)(Y01 + (size_t)(plb + p) * 128 + c8 * 8);
        float* d = &a_lds[p * 133 + c8 * 8];
        d[0] = bflo(u.x); d[1] = bfhi(u.x); d[2] = bflo(u.y); d[3] = bfhi(u.y);
        d[4] = bflo(u.z); d[5] = bfhi(u.z); d[6] = bflo(u.w); d[7] = bfhi(u.w);
    }
    __syncthreads();
    int lane = t & 63;
    int cg = __builtin_amdgcn_readfirstlane(threadIdx.x >> 6);
    int gate = cg >> 1, dbase = (cg & 1) * 32;
    {
        const float* wb = W2f + gate * 4096 + dbase;
        float acc[32];
        #pragma unroll
        for (int j = 0; j < 32; ++j) acc[j] = b2f[gate * 64 + dbase + j];
        const float* ar = &a_lds[lane * 133 + gate * 64];
        for (int c = 0; c < 64; ++c) {
            float a = ar[c];
            const float* w0 = wb + c * 64;
            #pragma unroll
            for (int j = 0; j < 32; ++j) acc[j] = fmaf(a, w0[j], acc[j]);
        }
        float* dst = &t_lds[lane * 133 + cg * 32];
        #pragma unroll
        for (int j = 0; j < 32; ++j) dst[j] = leaky(acc[j]);
    }
    __syncthreads();
    {
        const float* wb = W3f + gate * 4096 + dbase;
        float acc[32];
        #pragma unroll
        for (int j = 0; j < 32; ++j) acc[j] = b3f[gate * 64 + dbase + j];
        const float* tr = &t_lds[lane * 133 + gate * 64];
        for (int c = 0; c < 64; ++c) {
            float a = tr[c];
            const float* w0 = wb + c * 64;
            #pragma unroll
            for (int j = 0; j < 32; ++j) acc[j] = fmaf(a, w0[j], acc[j]);
        }
        int pl = plb + lane;
        int pg = p0 + pl;
        u32 o[16];
        if (gate == 0) {
            #pragma unroll
            for (int j = 0; j < 16; ++j) o[j] = pk2(sigm(acc[2 * j]), sigm(acc[2 * j + 1]));
            u16* dst = Z + (size_t)pl * 64 + dbase;
            #pragma unroll
            for (int q = 0; q < 4; ++q) ((uint4*)dst)[q] = *(uint4*)&o[q * 4];
        } else {
            const float* hp = h + (size_t)pg * 64 + dbase;
            float rh[32];
            #pragma unroll
            for (int j = 0; j < 32; ++j) rh[j] = sigm(acc[j]) * hp[j];
            #pragma unroll
            for (int j = 0; j < 16; ++j) o[j] = pk2(rh[2 * j], rh[2 * j + 1]);
            u16* dst = RH + (size_t)pl * 64 + dbase;
            #pragma unroll
            for (int q = 0; q < 4; ++q) ((uint4*)dst)[q] = *(uint4*)&o[q * 4];
        }
    }
}

// K4: P2[pl][d] (bf16) = b1[2][d] + sum_c [RH|x][p][c] * W1[2][c][d]
__global__ __launch_bounds__(256) void k_gemm_p2(
    const u16* __restrict__ RH, const float* __restrict__ x,
    const float* __restrict__ W1f, const float* __restrict__ b1f,
    u16* __restrict__ P2, int p0)
{
    __shared__ float a_lds[64 * 132];
    int t = threadIdx.x;
    int plb = blockIdx.x * 64;
    int pgb = p0 + plb;
    for (int i = 0; i < 2; ++i) {       // RH half (bf16, local rows)
        int id = t + i * 256;           // 0..511
        int p = id >> 3, c8 = id & 7;
        uint4 u = *(const uint4*)(RH + (size_t)(plb + p) * 64 + c8 * 8);
        float* d = &a_lds[p * 132 + c8 * 8];
        d[0] = bflo(u.x); d[1] = bfhi(u.x); d[2] = bflo(u.y); d[3] = bfhi(u.y);
        d[4] = bflo(u.z); d[5] = bfhi(u.z); d[6] = bflo(u.w); d[7] = bfhi(u.w);
    }
    for (int i = 0; i < 4; ++i) {       // x half (fp32, global rows)
        int id = t + i * 256;           // 0..1023
        int p = id >> 4, c4 = id & 15;
        float4 v = *(const float4*)(x + (size_t)(pgb + p) * 64 + c4 * 4);
        *(float4*)&a_lds[p * 132 + 64 + c4 * 4] = v;
    }
    __syncthreads();
    int lane = t & 63;
    int cg = __builtin_amdgcn_readfirstlane(threadIdx.x >> 6);
    int dbase = cg * 16;
    const float* wbase = W1f + 2 * 8384 + dbase;
    float acc[16];
    #pragma unroll
    for (int j = 0; j < 16; ++j) acc[j] = b1f[128 + dbase + j];
    const float4* arow = (const float4*)&a_lds[lane * 132];
    for (int c4 = 0; c4 < 32; ++c4) {
        float4 a = arow[c4];
        const float* w0 = wbase + c4 * 256;
        #pragma unroll
        for (int j = 0; j < 16; ++j) acc[j] = fmaf(a.x, w0[j], acc[j]);
        #pragma unroll
        for (int j = 0; j < 16; ++j) acc[j] = fmaf(a.y, w0[64 + j], acc[j]);
        #pragma unroll
        for (int j = 0; j < 16; ++j) acc[j] = fmaf(a.z, w0[128 + j], acc[j]);
        #pragma unroll
        for (int j = 0; j < 16; ++j) acc[j] = fmaf(a.w, w0[192 + j], acc[j]);
    }
    u16* dst = P2 + (size_t)(plb + lane) * 64 + dbase;
    u32 o[8];
    #pragma unroll
    for (int j = 0; j < 8; ++j) o[j] = pk2(acc[2 * j], acc[2 * j + 1]);
    #pragma unroll
    for (int q = 0; q < 2; ++q) ((uint4*)dst)[q] = *(uint4*)&o[q * 4];
}

// K5: gather + edge + maxpool, gate 2
__global__ __launch_bounds__(256) void k_pool2(
    const u16* __restrict__ P2, const float* __restrict__ W1f,
    const int* __restrict__ nidx, const float* __restrict__ ef,
    u16* __restrict__ Y2, int p0)
{
    int t = threadIdx.x;
    int l = t & 63;
    int wv = __builtin_amdgcn_readfirstlane(threadIdx.x >> 6);
    int pl = blockIdx.x * 4 + wv;
    int pg = p0 + pl;
    int rbase = ((pg >> 13) << 13) - p0;
    const float* W = W1f + 2 * 8384;
    float w0 = W[8192 + l], w1 = W[8256 + l], w2 = W[8320 + l];
    const int* ni = nidx + (size_t)pg * KNBR;
    const float* ep = ef + (size_t)pg * KNBR * 3;
    float m = -1e30f;
    #pragma unroll 8
    for (int k = 0; k < KNBR; ++k) {
        int lr = rbase + ni[k];
        float e0 = ep[k * 3 + 0];
        float e1 = ep[k * 3 + 1];
        float e2 = ep[k * 3 + 2];
        float v = bf2f(P2[(size_t)lr * 64 + l]) + e0 * w0 + e1 * w1 + e2 * w2;
        m = fmaxf(m, v);
    }
    Y2[(size_t)pl * 64 + l] = f2bf(leaky(m));
}

// K6: MLP gate 2 -> q = tanh, out = (1-z)*h + z*q  (fp32 out)
__global__ __launch_bounds__(256) void k_mlp2(
    const u16* __restrict__ Y2,
    const float* __restrict__ W2f, const float* __restrict__ b2f,
    const float* __restrict__ W3f, const float* __restrict__ b3f,
    const float* __restrict__ h, const u16* __restrict__ Z,
    float* __restrict__ out, int p0)
{
    __shared__ float a_lds[64 * 69];
    __shared__ float t_lds[64 * 69];
    int t = threadIdx.x;
    int plb = blockIdx.x * 64;
    for (int i = 0; i < 2; ++i) {
        int id = t + i * 256;           // 0..511
        int p = id >> 3, c8 = id & 7;
        uint4 u = *(const uint4*)(Y2 + (size_t)(plb + p) * 64 + c8 * 8);
        float* d = &a_lds[p * 69 + c8 * 8];
        d[0] = bflo(u.x); d[1] = bfhi(u.x); d[2] = bflo(u.y); d[3] = bfhi(u.y);
        d[4] = bflo(u.z); d[5] = bfhi(u.z); d[6] = bflo(u.w); d[7] = bfhi(u.w);
    }
    __syncthreads();
    int lane = t & 63;
    int cg = __builtin_amdgcn_readfirstlane(threadIdx.x >> 6);
    int dbase = cg * 16;
    float acc[16];
    {
        const float* wb = W2f + 2 * 4096 + dbase;
        #pragma unroll
        for (int j = 0; j < 16; ++j) acc[j] = b2f[128 + dbase + j];
        const float* ar = &a_lds[lane * 69];
        for (int c = 0; c < 64; ++c) {
            float a = ar[c];
            const float* w0 = wb + c * 64;
            #pragma unroll
            for (int j = 0; j < 16; ++j) acc[j] = fmaf(a, w0[j], acc[j]);
        }
        float* td = &t_lds[lane * 69 + dbase];
        #pragma unroll
        for (int j = 0; j < 16; ++j) td[j] = leaky(acc[j]);
    }
    __syncthreads();
    {
        const float* wb = W3f + 2 * 4096 + dbase;
        #pragma unroll
        for (int j = 0; j < 16; ++j) acc[j] = b3f[128 + dbase + j];
        const float* tr = &t_lds[lane * 69];
        for (int c = 0; c < 64; ++c) {
            float a = tr[c];
            const float* w0 = wb + c * 64;
            #pragma unroll
            for (int j = 0; j < 16; ++j) acc[j] = fmaf(a, w0[j], acc[j]);
        }
        int pl = plb + lane;
        int pg = p0 + pl;
        const float* hp = h + (size_t)pg * 64 + dbase;
        const u16* zp = Z + (size_t)pl * 64 + dbase;
        float* op = out + (size_t)pg * 64 + dbase;
        float o[16];
        #pragma unroll
        for (int j = 0; j < 16; ++j) {
            float q = tanhf(acc[j]);
            float z = bf2f(zp[j]);
            o[j] = (1.f - z) * hp[j] + z * q;
        }
        #pragma unroll
        for (int q4 = 0; q4 < 4; ++q4)
            *(float4*)&op[q4 * 4] = make_float4(o[q4*4], o[q4*4+1], o[q4*4+2], o[q4*4+3]);
    }
}

extern "C" void kernel_launch(void* const* d_in, const int* in_sizes, int n_in,
                              void* d_out, int out_size, void* d_ws, size_t ws_size,
                              hipStream_t stream)
{
    const float* h  = (const float*)d_in[0];
    const float* x  = (const float*)d_in[1];
    // d_in[2] = c (unused by the reference)
    const float* W1 = (const float*)d_in[3];
    const float* b1 = (const float*)d_in[4];
    const float* W2 = (const float*)d_in[5];
    const float* b2 = (const float*)d_in[6];
    const float* W3 = (const float*)d_in[7];
    const float* b3 = (const float*)d_in[8];
    const int* nidx = (const int*)d_in[9];
    const float* ef = (const float*)d_in[10];
    float* out = (float*)d_out;

    char* wsb = (char*)d_ws;
    size_t PN = (ws_size >= 32768ull * 512ull) ? 32768 : 8192;
    int passes = (int)(32768 / PN);

    u32* P01 = (u32*)wsb;                       // [PN][64] u32 (gate-interleaved bf16 pair)
    u16* Y01 = (u16*)(wsb + PN * 256);          // [PN][128] bf16
    u16* Z   = (u16*)wsb;                       // alias (P01 dead after K2)
    u16* RH  = (u16*)(wsb + PN * 128);          // alias P01 upper half
    u16* P2  = Y01;                             // alias (Y01 dead after K3)
    u16* Y2  = (u16*)((char*)Y01 + PN * 128);   // alias Y01 upper half

    for (int s = 0; s < passes; ++s) {
        int p0 = (int)(s * PN);
        dim3 gM((unsigned)(PN / 64));
        dim3 gP((unsigned)(PN / 4));
        k_gemm_p01<<<gM, 256, 0, stream>>>(h, x, W1, b1, P01, p0);
        k_pool01 <<<gP, 256, 0, stream>>>(P01, W1, nidx, ef, Y01, p0);
        k_mlp01  <<<gM, 256, 0, stream>>>(Y01, W2, b2, W3, b3, h, Z, RH, p0);
        k_gemm_p2<<<gM, 256, 0, stream>>>(RH, x, W1, b1, P2, p0);
        k_pool2  <<<gP, 256, 0, stream>>>(P2, W1, nidx, ef, Y2, p0);
        k_mlp2   <<<gM, 256, 0, stream>>>(Y2, W2, b2, W3, b3, h, Z, out, p0);
    }
}

// Round 5
// 225.711 us; speedup vs baseline: 1.6998x; 1.0152x over previous
//
#include <hip/hip_runtime.h>
#include <math.h>

typedef unsigned short u16;
typedef unsigned int u32;

#define KNBR 32

__device__ __forceinline__ float bf2f(u16 u) { return __uint_as_float((u32)u << 16); }
__device__ __forceinline__ float bflo(u32 u) { return __uint_as_float(u << 16); }
__device__ __forceinline__ float bfhi(u32 u) { return __uint_as_float(u & 0xffff0000u); }
__device__ __forceinline__ u16 f2bf(float f) {
    u32 u = __float_as_uint(f);
    return (u16)((u + 0x7fffu + ((u >> 16) & 1u)) >> 16);
}
__device__ __forceinline__ u32 pk2(float a, float b) {
    return (u32)f2bf(a) | ((u32)f2bf(b) << 16);
}
__device__ __forceinline__ float leaky(float v) { return v >= 0.f ? v : 0.1f * v; }
__device__ __forceinline__ float sigm(float v) { return 1.f / (1.f + expf(-v)); }

// W1: [3][131][64] fp32 (g*8384 + c*64 + d), b1: [3][64],
// W2/W3: [3][64][64] (g*4096 + c*64 + d), b2/b3: [3][64].
// P01: u32 rows of 64 (channel d holds pk2(gate0, gate1)).

// K1: both gates of layer-1 pre-activation. 512 thr = 8 waves, 64-pt tile,
// wave owns 8 channels x 2 gates.  2 blocks/CU -> 16 waves/CU.
__global__ __launch_bounds__(512) void k_gemm_p01(
    const float* __restrict__ h, const float* __restrict__ x,
    const float* __restrict__ W1f, const float* __restrict__ b1f,
    u32* __restrict__ P01, int p0)
{
    __shared__ float a_lds[64 * 132];
    int t = threadIdx.x;
    int plb = blockIdx.x * 64;
    int pgb = p0 + plb;
    for (int i = 0; i < 4; ++i) {
        int id = t + i * 512;           // 0..2047
        int p = id >> 5, c4 = id & 31;
        const float* src = (c4 < 16) ? (h + (size_t)(pgb + p) * 64 + c4 * 4)
                                     : (x + (size_t)(pgb + p) * 64 + (c4 - 16) * 4);
        float4 v = *(const float4*)src;
        *(float4*)&a_lds[p * 132 + c4 * 4] = v;
    }
    __syncthreads();
    int lane = t & 63;
    int cg = __builtin_amdgcn_readfirstlane(threadIdx.x >> 6);   // 0..7
    int dbase = cg * 8;
    const float* wg0 = W1f + dbase;             // gate 0
    const float* wg1 = W1f + 8384 + dbase;      // gate 1
    float acc0[8], acc1[8];
    #pragma unroll
    for (int j = 0; j < 8; ++j) { acc0[j] = b1f[dbase + j]; acc1[j] = b1f[64 + dbase + j]; }
    const float4* arow = (const float4*)&a_lds[lane * 132];
    for (int c4 = 0; c4 < 32; ++c4) {
        float4 a = arow[c4];
        const float* wa = wg0 + c4 * 256;
        const float* wb = wg1 + c4 * 256;
        #pragma unroll
        for (int j = 0; j < 8; ++j) acc0[j] = fmaf(a.x, wa[j], acc0[j]);
        #pragma unroll
        for (int j = 0; j < 8; ++j) acc0[j] = fmaf(a.y, wa[64 + j], acc0[j]);
        #pragma unroll
        for (int j = 0; j < 8; ++j) acc0[j] = fmaf(a.z, wa[128 + j], acc0[j]);
        #pragma unroll
        for (int j = 0; j < 8; ++j) acc0[j] = fmaf(a.w, wa[192 + j], acc0[j]);
        #pragma unroll
        for (int j = 0; j < 8; ++j) acc1[j] = fmaf(a.x, wb[j], acc1[j]);
        #pragma unroll
        for (int j = 0; j < 8; ++j) acc1[j] = fmaf(a.y, wb[64 + j], acc1[j]);
        #pragma unroll
        for (int j = 0; j < 8; ++j) acc1[j] = fmaf(a.z, wb[128 + j], acc1[j]);
        #pragma unroll
        for (int j = 0; j < 8; ++j) acc1[j] = fmaf(a.w, wb[192 + j], acc1[j]);
    }
    u32* dst = P01 + (size_t)(plb + lane) * 64 + dbase;
    u32 o[8];
    #pragma unroll
    for (int j = 0; j < 8; ++j) o[j] = pk2(acc0[j], acc1[j]);
    #pragma unroll
    for (int q = 0; q < 2; ++q) ((uint4*)dst)[q] = *(uint4*)&o[q * 4];
}

// K2: gather + edge-proj + maxpool, gates 0,1. one wave/point, lane = channel.
__global__ __launch_bounds__(256) void k_pool01(
    const u32* __restrict__ P01, const float* __restrict__ W1f,
    const int* __restrict__ nidx, const float* __restrict__ ef,
    u16* __restrict__ Y01, int p0)
{
    int t = threadIdx.x;
    int l = t & 63;
    int wv = __builtin_amdgcn_readfirstlane(threadIdx.x >> 6);
    int pl = blockIdx.x * 4 + wv;
    int pg = p0 + pl;
    int rbase = ((pg >> 13) << 13) - p0;
    float w00 = W1f[8192 + l], w01 = W1f[8256 + l], w02 = W1f[8320 + l];
    float w10 = W1f[16576 + l], w11 = W1f[16640 + l], w12 = W1f[16704 + l];
    const int* ni = nidx + (size_t)pg * KNBR;
    const float* ep = ef + (size_t)pg * KNBR * 3;
    float m0 = -1e30f, m1 = -1e30f;
    #pragma unroll 16
    for (int k = 0; k < KNBR; ++k) {
        int lr = rbase + ni[k];
        float e0 = ep[k * 3 + 0];
        float e1 = ep[k * 3 + 1];
        float e2 = ep[k * 3 + 2];
        u32 g = P01[(size_t)lr * 64 + l];
        float v0 = bflo(g) + e0 * w00 + e1 * w01 + e2 * w02;
        float v1 = bfhi(g) + e0 * w10 + e1 * w11 + e2 * w12;
        m0 = fmaxf(m0, v0);
        m1 = fmaxf(m1, v1);
    }
    Y01[(size_t)pl * 128 + l]      = f2bf(leaky(m0));
    Y01[(size_t)pl * 128 + 64 + l] = f2bf(leaky(m1));
}

// K3: 2-layer MLP gates 0,1 -> Z = sigmoid(g0), RH = sigmoid(g1)*h (both bf16).
// 512 thr = 8 waves; wave owns 16 channels of one gate.
__global__ __launch_bounds__(512) void k_mlp01(
    const u16* __restrict__ Y01,
    const float* __restrict__ W2f, const float* __restrict__ b2f,
    const float* __restrict__ W3f, const float* __restrict__ b3f,
    const float* __restrict__ h, u16* __restrict__ Z, u16* __restrict__ RH, int p0)
{
    __shared__ float a_lds[64 * 133];
    __shared__ float t_lds[64 * 133];
    int t = threadIdx.x;
    int plb = blockIdx.x * 64;
    for (int i = 0; i < 2; ++i) {
        int id = t + i * 512;           // 0..1023
        int p = id >> 4, c8 = id & 15;
        uint4 u = *(const uint4*)(Y01 + (size_t)(plb + p) * 128 + c8 * 8);
        float* d = &a_lds[p * 133 + c8 * 8];
        d[0] = bflo(u.x); d[1] = bfhi(u.x); d[2] = bflo(u.y); d[3] = bfhi(u.y);
        d[4] = bflo(u.z); d[5] = bfhi(u.z); d[6] = bflo(u.w); d[7] = bfhi(u.w);
    }
    __syncthreads();
    int lane = t & 63;
    int cg = __builtin_amdgcn_readfirstlane(threadIdx.x >> 6);   // 0..7
    int gate = cg >> 2, dbase = (cg & 3) * 16;
    {
        const float* wb = W2f + gate * 4096 + dbase;
        float acc[16];
        #pragma unroll
        for (int j = 0; j < 16; ++j) acc[j] = b2f[gate * 64 + dbase + j];
        const float* ar = &a_lds[lane * 133 + gate * 64];
        for (int c = 0; c < 64; ++c) {
            float a = ar[c];
            const float* w0 = wb + c * 64;
            #pragma unroll
            for (int j = 0; j < 16; ++j) acc[j] = fmaf(a, w0[j], acc[j]);
        }
        float* dst = &t_lds[lane * 133 + gate * 64 + dbase];
        #pragma unroll
        for (int j = 0; j < 16; ++j) dst[j] = leaky(acc[j]);
    }
    __syncthreads();
    {
        const float* wb = W3f + gate * 4096 + dbase;
        float acc[16];
        #pragma unroll
        for (int j = 0; j < 16; ++j) acc[j] = b3f[gate * 64 + dbase + j];
        const float* tr = &t_lds[lane * 133 + gate * 64];
        for (int c = 0; c < 64; ++c) {
            float a = tr[c];
            const float* w0 = wb + c * 64;
            #pragma unroll
            for (int j = 0; j < 16; ++j) acc[j] = fmaf(a, w0[j], acc[j]);
        }
        int pl = plb + lane;
        int pg = p0 + pl;
        u32 o[8];
        if (gate == 0) {
            #pragma unroll
            for (int j = 0; j < 8; ++j) o[j] = pk2(sigm(acc[2 * j]), sigm(acc[2 * j + 1]));
            u16* dst = Z + (size_t)pl * 64 + dbase;
            #pragma unroll
            for (int q = 0; q < 2; ++q) ((uint4*)dst)[q] = *(uint4*)&o[q * 4];
        } else {
            const float* hp = h + (size_t)pg * 64 + dbase;
            float rh[16];
            #pragma unroll
            for (int j = 0; j < 16; ++j) rh[j] = sigm(acc[j]) * hp[j];
            #pragma unroll
            for (int j = 0; j < 8; ++j) o[j] = pk2(rh[2 * j], rh[2 * j + 1]);
            u16* dst = RH + (size_t)pl * 64 + dbase;
            #pragma unroll
            for (int q = 0; q < 2; ++q) ((uint4*)dst)[q] = *(uint4*)&o[q * 4];
        }
    }
}

// K4: P2[pl][d] (bf16) = b1[2][d] + sum_c [RH|x][p][c] * W1[2][c][d]
// 512 thr = 8 waves; wave owns 8 channels.
__global__ __launch_bounds__(512) void k_gemm_p2(
    const u16* __restrict__ RH, const float* __restrict__ x,
    const float* __restrict__ W1f, const float* __restrict__ b1f,
    u16* __restrict__ P2, int p0)
{
    __shared__ float a_lds[64 * 132];
    int t = threadIdx.x;
    int plb = blockIdx.x * 64;
    int pgb = p0 + plb;
    {                                    // RH half (bf16, local rows): 512 chunks
        int p = t >> 3, c8 = t & 7;
        uint4 u = *(const uint4*)(RH + (size_t)(plb + p) * 64 + c8 * 8);
        float* d = &a_lds[p * 132 + c8 * 8];
        d[0] = bflo(u.x); d[1] = bfhi(u.x); d[2] = bflo(u.y); d[3] = bfhi(u.y);
        d[4] = bflo(u.z); d[5] = bfhi(u.z); d[6] = bflo(u.w); d[7] = bfhi(u.w);
    }
    for (int i = 0; i < 2; ++i) {        // x half (fp32, global rows): 1024 chunks
        int id = t + i * 512;
        int p = id >> 4, c4 = id & 15;
        float4 v = *(const float4*)(x + (size_t)(pgb + p) * 64 + c4 * 4);
        *(float4*)&a_lds[p * 132 + 64 + c4 * 4] = v;
    }
    __syncthreads();
    int lane = t & 63;
    int cg = __builtin_amdgcn_readfirstlane(threadIdx.x >> 6);   // 0..7
    int dbase = cg * 8;
    const float* wbase = W1f + 2 * 8384 + dbase;
    float acc[8];
    #pragma unroll
    for (int j = 0; j < 8; ++j) acc[j] = b1f[128 + dbase + j];
    const float4* arow = (const float4*)&a_lds[lane * 132];
    for (int c4 = 0; c4 < 32; ++c4) {
        float4 a = arow[c4];
        const float* w0 = wbase + c4 * 256;
        #pragma unroll
        for (int j = 0; j < 8; ++j) acc[j] = fmaf(a.x, w0[j], acc[j]);
        #pragma unroll
        for (int j = 0; j < 8; ++j) acc[j] = fmaf(a.y, w0[64 + j], acc[j]);
        #pragma unroll
        for (int j = 0; j < 8; ++j) acc[j] = fmaf(a.z, w0[128 + j], acc[j]);
        #pragma unroll
        for (int j = 0; j < 8; ++j) acc[j] = fmaf(a.w, w0[192 + j], acc[j]);
    }
    u16* dst = P2 + (size_t)(plb + lane) * 64 + dbase;
    u32 o[4];
    #pragma unroll
    for (int j = 0; j < 4; ++j) o[j] = pk2(acc[2 * j], acc[2 * j + 1]);
    *(uint4*)dst = *(uint4*)&o[0];
}

// K5: gather + edge + maxpool, gate 2
__global__ __launch_bounds__(256) void k_pool2(
    const u16* __restrict__ P2, const float* __restrict__ W1f,
    const int* __restrict__ nidx, const float* __restrict__ ef,
    u16* __restrict__ Y2, int p0)
{
    int t = threadIdx.x;
    int l = t & 63;
    int wv = __builtin_amdgcn_readfirstlane(threadIdx.x >> 6);
    int pl = blockIdx.x * 4 + wv;
    int pg = p0 + pl;
    int rbase = ((pg >> 13) << 13) - p0;
    const float* W = W1f + 2 * 8384;
    float w0 = W[8192 + l], w1 = W[8256 + l], w2 = W[8320 + l];
    const int* ni = nidx + (size_t)pg * KNBR;
    const float* ep = ef + (size_t)pg * KNBR * 3;
    float m = -1e30f;
    #pragma unroll 16
    for (int k = 0; k < KNBR; ++k) {
        int lr = rbase + ni[k];
        float e0 = ep[k * 3 + 0];
        float e1 = ep[k * 3 + 1];
        float e2 = ep[k * 3 + 2];
        float v = bf2f(P2[(size_t)lr * 64 + l]) + e0 * w0 + e1 * w1 + e2 * w2;
        m = fmaxf(m, v);
    }
    Y2[(size_t)pl * 64 + l] = f2bf(leaky(m));
}

// K6: MLP gate 2 -> q = tanh, out = (1-z)*h + z*q (fp32 out).
// 512 thr = 8 waves; wave owns 8 channels.
__global__ __launch_bounds__(512) void k_mlp2(
    const u16* __restrict__ Y2,
    const float* __restrict__ W2f, const float* __restrict__ b2f,
    const float* __restrict__ W3f, const float* __restrict__ b3f,
    const float* __restrict__ h, const u16* __restrict__ Z,
    float* __restrict__ out, int p0)
{
    __shared__ float a_lds[64 * 69];
    __shared__ float t_lds[64 * 69];
    int t = threadIdx.x;
    int plb = blockIdx.x * 64;
    {
        int p = t >> 3, c8 = t & 7;      // 512 chunks
        uint4 u = *(const uint4*)(Y2 + (size_t)(plb + p) * 64 + c8 * 8);
        float* d = &a_lds[p * 69 + c8 * 8];
        d[0] = bflo(u.x); d[1] = bfhi(u.x); d[2] = bflo(u.y); d[3] = bfhi(u.y);
        d[4] = bflo(u.z); d[5] = bfhi(u.z); d[6] = bflo(u.w); d[7] = bfhi(u.w);
    }
    __syncthreads();
    int lane = t & 63;
    int cg = __builtin_amdgcn_readfirstlane(threadIdx.x >> 6);   // 0..7
    int dbase = cg * 8;
    float acc[8];
    {
        const float* wb = W2f + 2 * 4096 + dbase;
        #pragma unroll
        for (int j = 0; j < 8; ++j) acc[j] = b2f[128 + dbase + j];
        const float* ar = &a_lds[lane * 69];
        for (int c = 0; c < 64; ++c) {
            float a = ar[c];
            const float* w0 = wb + c * 64;
            #pragma unroll
            for (int j = 0; j < 8; ++j) acc[j] = fmaf(a, w0[j], acc[j]);
        }
        float* td = &t_lds[lane * 69 + dbase];
        #pragma unroll
        for (int j = 0; j < 8; ++j) td[j] = leaky(acc[j]);
    }
    __syncthreads();
    {
        const float* wb = W3f + 2 * 4096 + dbase;
        #pragma unroll
        for (int j = 0; j < 8; ++j) acc[j] = b3f[128 + dbase + j];
        const float* tr = &t_lds[lane * 69];
        for (int c = 0; c < 64; ++c) {
            float a = tr[c];
            const float* w0 = wb + c * 64;
            #pragma unroll
            for (int j = 0; j < 8; ++j) acc[j] = fmaf(a, w0[j], acc[j]);
        }
        int pl = plb + lane;
        int pg = p0 + pl;
        const float* hp = h + (size_t)pg * 64 + dbase;
        const u16* zp = Z + (size_t)pl * 64 + dbase;
        float* op = out + (size_t)pg * 64 + dbase;
        float o[8];
        #pragma unroll
        for (int j = 0; j < 8; ++j) {
            float q = tanhf(acc[j]);
            float z = bf2f(zp[j]);
            o[j] = (1.f - z) * hp[j] + z * q;
        }
        #pragma unroll
        for (int q4 = 0; q4 < 2; ++q4)
            *(float4*)&op[q4 * 4] = make_float4(o[q4*4], o[q4*4+1], o[q4*4+2], o[q4*4+3]);
    }
}

extern "C" void kernel_launch(void* const* d_in, const int* in_sizes, int n_in,
                              void* d_out, int out_size, void* d_ws, size_t ws_size,
                              hipStream_t stream)
{
    const float* h  = (const float*)d_in[0];
    const float* x  = (const float*)d_in[1];
    // d_in[2] = c (unused by the reference)
    const float* W1 = (const float*)d_in[3];
    const float* b1 = (const float*)d_in[4];
    const float* W2 = (const float*)d_in[5];
    const float* b2 = (const float*)d_in[6];
    const float* W3 = (const float*)d_in[7];
    const float* b3 = (const float*)d_in[8];
    const int* nidx = (const int*)d_in[9];
    const float* ef = (const float*)d_in[10];
    float* out = (float*)d_out;

    char* wsb = (char*)d_ws;
    size_t PN = (ws_size >= 32768ull * 512ull) ? 32768 : 8192;
    int passes = (int)(32768 / PN);

    u32* P01 = (u32*)wsb;                       // [PN][64] u32 (gate-interleaved bf16 pair)
    u16* Y01 = (u16*)(wsb + PN * 256);          // [PN][128] bf16
    u16* Z   = (u16*)wsb;                       // alias (P01 dead after K2)
    u16* RH  = (u16*)(wsb + PN * 128);          // alias P01 upper half
    u16* P2  = Y01;                             // alias (Y01 dead after K3)
    u16* Y2  = (u16*)((char*)Y01 + PN * 128);   // alias Y01 upper half

    for (int s = 0; s < passes; ++s) {
        int p0 = (int)(s * PN);
        dim3 gM((unsigned)(PN / 64));
        dim3 gP((unsigned)(PN / 4));
        k_gemm_p01<<<gM, 512, 0, stream>>>(h, x, W1, b1, P01, p0);
        k_pool01 <<<gP, 256, 0, stream>>>(P01, W1, nidx, ef, Y01, p0);
        k_mlp01  <<<gM, 512, 0, stream>>>(Y01, W2, b2, W3, b3, h, Z, RH, p0);
        k_gemm_p2<<<gM, 512, 0, stream>>>(RH, x, W1, b1, P2, p0);
        k_pool2  <<<gP, 256, 0, stream>>>(P2, W1, nidx, ef, Y2, p0);
        k_mlp2   <<<gM, 512, 0, stream>>>(Y2, W2, b2, W3, b3, h, Z, out, p0);
    }
}

// Round 6
// 218.385 us; speedup vs baseline: 1.7569x; 1.0335x over previous
//
#include <hip/hip_runtime.h>
#include <math.h>

typedef unsigned short u16;
typedef unsigned int u32;

#define KNBR 32

__device__ __forceinline__ float bf2f(u16 u) { return __uint_as_float((u32)u << 16); }
__device__ __forceinline__ float bflo(u32 u) { return __uint_as_float(u << 16); }
__device__ __forceinline__ float bfhi(u32 u) { return __uint_as_float(u & 0xffff0000u); }
__device__ __forceinline__ u16 f2bf(float f) {
    u32 u = __float_as_uint(f);
    return (u16)((u + 0x7fffu + ((u >> 16) & 1u)) >> 16);
}
__device__ __forceinline__ u32 pk2(float a, float b) {
    return (u32)f2bf(a) | ((u32)f2bf(b) << 16);
}
__device__ __forceinline__ float leaky(float v) { return v >= 0.f ? v : 0.1f * v; }
__device__ __forceinline__ float sigm(float v) { return 1.f / (1.f + expf(-v)); }

// W1: [3][131][64] fp32 (g*8384 + c*64 + d), b1: [3][64],
// W2/W3: [3][64][64] (g*4096 + c*64 + d), b2/b3: [3][64].
// P01: u32 rows of 64 (channel d holds pk2(gate0, gate1)).

// ---------------- K1: layer-1 preact, gates 0+1. ----------------
// 64-pt tile, 8 waves; lane = point; wave owns 8 channels x 2 gates.
// Weights staged in LDS fp32 in two K-halves; activations bf16-packed in LDS.
__global__ __launch_bounds__(512) void k_gemm_p01(
    const float* __restrict__ h, const float* __restrict__ x,
    const float* __restrict__ W1f, const float* __restrict__ b1f,
    u32* __restrict__ P01, int p0)
{
    __shared__ u32 a_lds[64 * 65];          // [pt][c-pair 0..63], pad 65
    __shared__ float w_lds[2][64 * 64];     // [gate][c(64-row half)][d]
    int t = threadIdx.x;
    int plb = blockIdx.x * 64;
    int pgb = p0 + plb;
    // stage activations: 4096 u32 words (h|x fp32 -> bf16 pairs)
    for (int i = 0; i < 8; ++i) {
        int id = t + i * 512;               // 0..4095
        int p = id >> 6, cw = id & 63;
        const float* src = (cw < 32) ? (h + (size_t)(pgb + p) * 64 + cw * 2)
                                     : (x + (size_t)(pgb + p) * 64 + (cw - 32) * 2);
        float2 v = *(const float2*)src;
        a_lds[p * 65 + cw] = pk2(v.x, v.y);
    }
    int lane = t & 63;
    int cg = __builtin_amdgcn_readfirstlane(threadIdx.x >> 6);   // 0..7
    int dbase = cg * 8;
    float acc0[8], acc1[8];
    #pragma unroll
    for (int j = 0; j < 8; ++j) { acc0[j] = b1f[dbase + j]; acc1[j] = b1f[64 + dbase + j]; }
    for (int half = 0; half < 2; ++half) {
        __syncthreads();    // a_lds ready (half0) / prior compute done (half1)
        for (int i = 0; i < 4; ++i) {       // stage 2048 float4 of weights
            int id = t + i * 512;
            int g = id >> 10;               // 1024 float4 per gate
            int r = (id >> 4) & 63;
            int d4 = id & 15;
            float4 wv = *(const float4*)(W1f + g * 8384 + (half * 64 + r) * 64 + d4 * 4);
            *(float4*)&w_lds[g][r * 64 + d4 * 4] = wv;
        }
        __syncthreads();
        const u32* arow = &a_lds[lane * 65 + half * 32];
        #pragma unroll 4
        for (int cw = 0; cw < 32; ++cw) {
            u32 aw = arow[cw];
            float a0 = bflo(aw), a1 = bfhi(aw);
            const float4* wr00 = (const float4*)&w_lds[0][(2 * cw) * 64 + dbase];
            const float4* wr01 = (const float4*)&w_lds[0][(2 * cw + 1) * 64 + dbase];
            const float4* wr10 = (const float4*)&w_lds[1][(2 * cw) * 64 + dbase];
            const float4* wr11 = (const float4*)&w_lds[1][(2 * cw + 1) * 64 + dbase];
            float4 w0a = wr00[0], w0b = wr00[1], w1a = wr01[0], w1b = wr01[1];
            float4 g0a = wr10[0], g0b = wr10[1], g1a = wr11[0], g1b = wr11[1];
            acc0[0] = fmaf(a0, w0a.x, acc0[0]); acc0[1] = fmaf(a0, w0a.y, acc0[1]);
            acc0[2] = fmaf(a0, w0a.z, acc0[2]); acc0[3] = fmaf(a0, w0a.w, acc0[3]);
            acc0[4] = fmaf(a0, w0b.x, acc0[4]); acc0[5] = fmaf(a0, w0b.y, acc0[5]);
            acc0[6] = fmaf(a0, w0b.z, acc0[6]); acc0[7] = fmaf(a0, w0b.w, acc0[7]);
            acc0[0] = fmaf(a1, w1a.x, acc0[0]); acc0[1] = fmaf(a1, w1a.y, acc0[1]);
            acc0[2] = fmaf(a1, w1a.z, acc0[2]); acc0[3] = fmaf(a1, w1a.w, acc0[3]);
            acc0[4] = fmaf(a1, w1b.x, acc0[4]); acc0[5] = fmaf(a1, w1b.y, acc0[5]);
            acc0[6] = fmaf(a1, w1b.z, acc0[6]); acc0[7] = fmaf(a1, w1b.w, acc0[7]);
            acc1[0] = fmaf(a0, g0a.x, acc1[0]); acc1[1] = fmaf(a0, g0a.y, acc1[1]);
            acc1[2] = fmaf(a0, g0a.z, acc1[2]); acc1[3] = fmaf(a0, g0a.w, acc1[3]);
            acc1[4] = fmaf(a0, g0b.x, acc1[4]); acc1[5] = fmaf(a0, g0b.y, acc1[5]);
            acc1[6] = fmaf(a0, g0b.z, acc1[6]); acc1[7] = fmaf(a0, g0b.w, acc1[7]);
            acc1[0] = fmaf(a1, g1a.x, acc1[0]); acc1[1] = fmaf(a1, g1a.y, acc1[1]);
            acc1[2] = fmaf(a1, g1a.z, acc1[2]); acc1[3] = fmaf(a1, g1a.w, acc1[3]);
            acc1[4] = fmaf(a1, g1b.x, acc1[4]); acc1[5] = fmaf(a1, g1b.y, acc1[5]);
            acc1[6] = fmaf(a1, g1b.z, acc1[6]); acc1[7] = fmaf(a1, g1b.w, acc1[7]);
        }
    }
    u32* dst = P01 + (size_t)(plb + lane) * 64 + dbase;
    u32 o[8];
    #pragma unroll
    for (int j = 0; j < 8; ++j) o[j] = pk2(acc0[j], acc1[j]);
    #pragma unroll
    for (int q = 0; q < 2; ++q) ((uint4*)dst)[q] = *(uint4*)&o[q * 4];
}

// ---------------- K2: gather + edge-proj + maxpool, gates 0,1 ----------------
__global__ __launch_bounds__(256) void k_pool01(
    const u32* __restrict__ P01, const float* __restrict__ W1f,
    const int* __restrict__ nidx, const float* __restrict__ ef,
    u16* __restrict__ Y01, int p0)
{
    int t = threadIdx.x;
    int l = t & 63;
    int wv = __builtin_amdgcn_readfirstlane(threadIdx.x >> 6);
    int pl = blockIdx.x * 4 + wv;
    int pg = p0 + pl;
    int rbase = ((pg >> 13) << 13) - p0;
    float w00 = W1f[8192 + l], w01 = W1f[8256 + l], w02 = W1f[8320 + l];
    float w10 = W1f[16576 + l], w11 = W1f[16640 + l], w12 = W1f[16704 + l];
    const int* ni = nidx + (size_t)pg * KNBR;
    const float* ep = ef + (size_t)pg * KNBR * 3;
    float m0 = -1e30f, m1 = -1e30f;
    #pragma unroll 16
    for (int k = 0; k < KNBR; ++k) {
        int lr = rbase + ni[k];
        float e0 = ep[k * 3 + 0];
        float e1 = ep[k * 3 + 1];
        float e2 = ep[k * 3 + 2];
        u32 g = P01[(size_t)lr * 64 + l];
        float v0 = bflo(g) + e0 * w00 + e1 * w01 + e2 * w02;
        float v1 = bfhi(g) + e0 * w10 + e1 * w11 + e2 * w12;
        m0 = fmaxf(m0, v0);
        m1 = fmaxf(m1, v1);
    }
    Y01[(size_t)pl * 128 + l]      = f2bf(leaky(m0));
    Y01[(size_t)pl * 128 + 64 + l] = f2bf(leaky(m1));
}

// ---------------- K3: 2-layer MLP gates 0,1 -> Z, RH ----------------
// lane = point; wave owns 16 channels of one gate. W2 then W3 staged in LDS.
__global__ __launch_bounds__(512) void k_mlp01(
    const u16* __restrict__ Y01,
    const float* __restrict__ W2f, const float* __restrict__ b2f,
    const float* __restrict__ W3f, const float* __restrict__ b3f,
    const float* __restrict__ h, u16* __restrict__ Z, u16* __restrict__ RH, int p0)
{
    __shared__ u32 a_lds[64 * 65];          // [pt][c-pair 0..63] (g0: 0..31, g1: 32..63)
    __shared__ float w_lds[2][64 * 64];     // [gate][c][d]
    int t = threadIdx.x;
    int plb = blockIdx.x * 64;
    const u32* Yw = (const u32*)Y01;
    for (int i = 0; i < 8; ++i) {
        int id = t + i * 512;
        int p = id >> 6, cw = id & 63;
        a_lds[p * 65 + cw] = Yw[(size_t)(plb + p) * 64 + cw];
    }
    for (int i = 0; i < 4; ++i) {           // stage W2 (both gates)
        int id = t + i * 512;
        int g = id >> 10, r = (id >> 4) & 63, d4 = id & 15;
        float4 wv = *(const float4*)(W2f + g * 4096 + r * 64 + d4 * 4);
        *(float4*)&w_lds[g][r * 64 + d4 * 4] = wv;
    }
    __syncthreads();
    int lane = t & 63;
    int cg = __builtin_amdgcn_readfirstlane(threadIdx.x >> 6);
    int gate = cg >> 2, dbase = (cg & 3) * 16;
    float acc[16];
    #pragma unroll
    for (int j = 0; j < 16; ++j) acc[j] = b2f[gate * 64 + dbase + j];
    {
        const u32* arow = &a_lds[lane * 65 + gate * 32];
        #pragma unroll 4
        for (int cw = 0; cw < 32; ++cw) {
            u32 aw = arow[cw];
            float a0 = bflo(aw), a1 = bfhi(aw);
            const float4* wr0 = (const float4*)&w_lds[gate][(2 * cw) * 64 + dbase];
            const float4* wr1 = (const float4*)&w_lds[gate][(2 * cw + 1) * 64 + dbase];
            #pragma unroll
            for (int q = 0; q < 4; ++q) {
                float4 w0 = wr0[q], w1 = wr1[q];
                acc[q*4+0] = fmaf(a0, w0.x, acc[q*4+0]); acc[q*4+1] = fmaf(a0, w0.y, acc[q*4+1]);
                acc[q*4+2] = fmaf(a0, w0.z, acc[q*4+2]); acc[q*4+3] = fmaf(a0, w0.w, acc[q*4+3]);
                acc[q*4+0] = fmaf(a1, w1.x, acc[q*4+0]); acc[q*4+1] = fmaf(a1, w1.y, acc[q*4+1]);
                acc[q*4+2] = fmaf(a1, w1.z, acc[q*4+2]); acc[q*4+3] = fmaf(a1, w1.w, acc[q*4+3]);
            }
        }
    }
    __syncthreads();                        // all layer-1 reads of a_lds/w_lds done
    {                                       // t into a_lds (bf16 pairs), same word slots
        u32* tw = &a_lds[lane * 65 + gate * 32 + (dbase >> 1)];
        #pragma unroll
        for (int j = 0; j < 8; ++j) tw[j] = pk2(leaky(acc[2 * j]), leaky(acc[2 * j + 1]));
    }
    for (int i = 0; i < 4; ++i) {           // restage W3
        int id = t + i * 512;
        int g = id >> 10, r = (id >> 4) & 63, d4 = id & 15;
        float4 wv = *(const float4*)(W3f + g * 4096 + r * 64 + d4 * 4);
        *(float4*)&w_lds[g][r * 64 + d4 * 4] = wv;
    }
    __syncthreads();
    #pragma unroll
    for (int j = 0; j < 16; ++j) acc[j] = b3f[gate * 64 + dbase + j];
    {
        const u32* arow = &a_lds[lane * 65 + gate * 32];
        #pragma unroll 4
        for (int cw = 0; cw < 32; ++cw) {
            u32 aw = arow[cw];
            float a0 = bflo(aw), a1 = bfhi(aw);
            const float4* wr0 = (const float4*)&w_lds[gate][(2 * cw) * 64 + dbase];
            const float4* wr1 = (const float4*)&w_lds[gate][(2 * cw + 1) * 64 + dbase];
            #pragma unroll
            for (int q = 0; q < 4; ++q) {
                float4 w0 = wr0[q], w1 = wr1[q];
                acc[q*4+0] = fmaf(a0, w0.x, acc[q*4+0]); acc[q*4+1] = fmaf(a0, w0.y, acc[q*4+1]);
                acc[q*4+2] = fmaf(a0, w0.z, acc[q*4+2]); acc[q*4+3] = fmaf(a0, w0.w, acc[q*4+3]);
                acc[q*4+0] = fmaf(a1, w1.x, acc[q*4+0]); acc[q*4+1] = fmaf(a1, w1.y, acc[q*4+1]);
                acc[q*4+2] = fmaf(a1, w1.z, acc[q*4+2]); acc[q*4+3] = fmaf(a1, w1.w, acc[q*4+3]);
            }
        }
    }
    int pl = plb + lane;
    int pg = p0 + pl;
    u32 o[8];
    if (gate == 0) {
        #pragma unroll
        for (int j = 0; j < 8; ++j) o[j] = pk2(sigm(acc[2 * j]), sigm(acc[2 * j + 1]));
        u16* dst = Z + (size_t)pl * 64 + dbase;
        #pragma unroll
        for (int q = 0; q < 2; ++q) ((uint4*)dst)[q] = *(uint4*)&o[q * 4];
    } else {
        const float* hp = h + (size_t)pg * 64 + dbase;
        float rh[16];
        #pragma unroll
        for (int j = 0; j < 16; ++j) rh[j] = sigm(acc[j]) * hp[j];
        #pragma unroll
        for (int j = 0; j < 8; ++j) o[j] = pk2(rh[2 * j], rh[2 * j + 1]);
        u16* dst = RH + (size_t)pl * 64 + dbase;
        #pragma unroll
        for (int q = 0; q < 2; ++q) ((uint4*)dst)[q] = *(uint4*)&o[q * 4];
    }
}

// ---------------- K4: layer-1 preact, gate 2 ----------------
__global__ __launch_bounds__(512) void k_gemm_p2(
    const u16* __restrict__ RH, const float* __restrict__ x,
    const float* __restrict__ W1f, const float* __restrict__ b1f,
    u16* __restrict__ P2, int p0)
{
    __shared__ u32 a_lds[64 * 65];
    __shared__ float w_lds[64 * 64];        // gate-2 rows, per K-half
    int t = threadIdx.x;
    int plb = blockIdx.x * 64;
    int pgb = p0 + plb;
    const u32* RHw = (const u32*)RH;
    for (int i = 0; i < 8; ++i) {
        int id = t + i * 512;
        int p = id >> 6, cw = id & 63;
        u32 w;
        if (cw < 32) w = RHw[(size_t)(plb + p) * 32 + cw];
        else {
            float2 v = *(const float2*)(x + (size_t)(pgb + p) * 64 + (cw - 32) * 2);
            w = pk2(v.x, v.y);
        }
        a_lds[p * 65 + cw] = w;
    }
    int lane = t & 63;
    int cg = __builtin_amdgcn_readfirstlane(threadIdx.x >> 6);
    int dbase = cg * 8;
    float acc[8];
    #pragma unroll
    for (int j = 0; j < 8; ++j) acc[j] = b1f[128 + dbase + j];
    for (int half = 0; half < 2; ++half) {
        __syncthreads();
        for (int i = 0; i < 2; ++i) {       // 1024 float4
            int id = t + i * 512;
            int r = (id >> 4) & 63, d4 = id & 15;
            float4 wv = *(const float4*)(W1f + 2 * 8384 + (half * 64 + r) * 64 + d4 * 4);
            *(float4*)&w_lds[r * 64 + d4 * 4] = wv;
        }
        __syncthreads();
        const u32* arow = &a_lds[lane * 65 + half * 32];
        #pragma unroll 4
        for (int cw = 0; cw < 32; ++cw) {
            u32 aw = arow[cw];
            float a0 = bflo(aw), a1 = bfhi(aw);
            const float4* wr0 = (const float4*)&w_lds[(2 * cw) * 64 + dbase];
            const float4* wr1 = (const float4*)&w_lds[(2 * cw + 1) * 64 + dbase];
            #pragma unroll
            for (int q = 0; q < 2; ++q) {
                float4 w0 = wr0[q], w1 = wr1[q];
                acc[q*4+0] = fmaf(a0, w0.x, acc[q*4+0]); acc[q*4+1] = fmaf(a0, w0.y, acc[q*4+1]);
                acc[q*4+2] = fmaf(a0, w0.z, acc[q*4+2]); acc[q*4+3] = fmaf(a0, w0.w, acc[q*4+3]);
                acc[q*4+0] = fmaf(a1, w1.x, acc[q*4+0]); acc[q*4+1] = fmaf(a1, w1.y, acc[q*4+1]);
                acc[q*4+2] = fmaf(a1, w1.z, acc[q*4+2]); acc[q*4+3] = fmaf(a1, w1.w, acc[q*4+3]);
            }
        }
    }
    u16* dst = P2 + (size_t)(plb + lane) * 64 + dbase;
    u32 o[4];
    #pragma unroll
    for (int j = 0; j < 4; ++j) o[j] = pk2(acc[2 * j], acc[2 * j + 1]);
    *(uint4*)dst = *(uint4*)&o[0];
}

// ---------------- K5: gather + edge + maxpool, gate 2 ----------------
__global__ __launch_bounds__(256) void k_pool2(
    const u16* __restrict__ P2, const float* __restrict__ W1f,
    const int* __restrict__ nidx, const float* __restrict__ ef,
    u16* __restrict__ Y2, int p0)
{
    int t = threadIdx.x;
    int l = t & 63;
    int wv = __builtin_amdgcn_readfirstlane(threadIdx.x >> 6);
    int pl = blockIdx.x * 4 + wv;
    int pg = p0 + pl;
    int rbase = ((pg >> 13) << 13) - p0;
    const float* W = W1f + 2 * 8384;
    float w0 = W[8192 + l], w1 = W[8256 + l], w2 = W[8320 + l];
    const int* ni = nidx + (size_t)pg * KNBR;
    const float* ep = ef + (size_t)pg * KNBR * 3;
    float m = -1e30f;
    #pragma unroll 16
    for (int k = 0; k < KNBR; ++k) {
        int lr = rbase + ni[k];
        float e0 = ep[k * 3 + 0];
        float e1 = ep[k * 3 + 1];
        float e2 = ep[k * 3 + 2];
        float v = bf2f(P2[(size_t)lr * 64 + l]) + e0 * w0 + e1 * w1 + e2 * w2;
        m = fmaxf(m, v);
    }
    Y2[(size_t)pl * 64 + l] = f2bf(leaky(m));
}

// ---------------- K6: MLP gate 2 -> q = tanh, out = (1-z)*h + z*q ----------------
__global__ __launch_bounds__(512) void k_mlp2(
    const u16* __restrict__ Y2,
    const float* __restrict__ W2f, const float* __restrict__ b2f,
    const float* __restrict__ W3f, const float* __restrict__ b3f,
    const float* __restrict__ h, const u16* __restrict__ Z,
    float* __restrict__ out, int p0)
{
    __shared__ u32 a_lds[64 * 33];          // [pt][c-pair 0..31], pad 33
    __shared__ float w_lds[64 * 64];        // W2[2] then W3[2]
    int t = threadIdx.x;
    int plb = blockIdx.x * 64;
    const u32* Yw = (const u32*)Y2;
    for (int i = 0; i < 4; ++i) {
        int id = t + i * 512;               // 0..2047
        int p = id >> 5, cw = id & 31;
        a_lds[p * 33 + cw] = Yw[(size_t)(plb + p) * 32 + cw];
    }
    for (int i = 0; i < 2; ++i) {           // stage W2[2]
        int id = t + i * 512;
        int r = (id >> 4) & 63, d4 = id & 15;
        float4 wv = *(const float4*)(W2f + 2 * 4096 + r * 64 + d4 * 4);
        *(float4*)&w_lds[r * 64 + d4 * 4] = wv;
    }
    __syncthreads();
    int lane = t & 63;
    int cg = __builtin_amdgcn_readfirstlane(threadIdx.x >> 6);
    int dbase = cg * 8;
    float acc[8];
    #pragma unroll
    for (int j = 0; j < 8; ++j) acc[j] = b2f[128 + dbase + j];
    {
        const u32* arow = &a_lds[lane * 33];
        #pragma unroll 4
        for (int cw = 0; cw < 32; ++cw) {
            u32 aw = arow[cw];
            float a0 = bflo(aw), a1 = bfhi(aw);
            const float4* wr0 = (const float4*)&w_lds[(2 * cw) * 64 + dbase];
            const float4* wr1 = (const float4*)&w_lds[(2 * cw + 1) * 64 + dbase];
            #pragma unroll
            for (int q = 0; q < 2; ++q) {
                float4 w0 = wr0[q], w1 = wr1[q];
                acc[q*4+0] = fmaf(a0, w0.x, acc[q*4+0]); acc[q*4+1] = fmaf(a0, w0.y, acc[q*4+1]);
                acc[q*4+2] = fmaf(a0, w0.z, acc[q*4+2]); acc[q*4+3] = fmaf(a0, w0.w, acc[q*4+3]);
                acc[q*4+0] = fmaf(a1, w1.x, acc[q*4+0]); acc[q*4+1] = fmaf(a1, w1.y, acc[q*4+1]);
                acc[q*4+2] = fmaf(a1, w1.z, acc[q*4+2]); acc[q*4+3] = fmaf(a1, w1.w, acc[q*4+3]);
            }
        }
    }
    __syncthreads();
    {
        u32* tw = &a_lds[lane * 33 + (dbase >> 1)];
        #pragma unroll
        for (int j = 0; j < 4; ++j) tw[j] = pk2(leaky(acc[2 * j]), leaky(acc[2 * j + 1]));
    }
    for (int i = 0; i < 2; ++i) {           // restage W3[2]
        int id = t + i * 512;
        int r = (id >> 4) & 63, d4 = id & 15;
        float4 wv = *(const float4*)(W3f + 2 * 4096 + r * 64 + d4 * 4);
        *(float4*)&w_lds[r * 64 + d4 * 4] = wv;
    }
    __syncthreads();
    #pragma unroll
    for (int j = 0; j < 8; ++j) acc[j] = b3f[128 + dbase + j];
    {
        const u32* arow = &a_lds[lane * 33];
        #pragma unroll 4
        for (int cw = 0; cw < 32; ++cw) {
            u32 aw = arow[cw];
            float a0 = bflo(aw), a1 = bfhi(aw);
            const float4* wr0 = (const float4*)&w_lds[(2 * cw) * 64 + dbase];
            const float4* wr1 = (const float4*)&w_lds[(2 * cw + 1) * 64 + dbase];
            #pragma unroll
            for (int q = 0; q < 2; ++q) {
                float4 w0 = wr0[q], w1 = wr1[q];
                acc[q*4+0] = fmaf(a0, w0.x, acc[q*4+0]); acc[q*4+1] = fmaf(a0, w0.y, acc[q*4+1]);
                acc[q*4+2] = fmaf(a0, w0.z, acc[q*4+2]); acc[q*4+3] = fmaf(a0, w0.w, acc[q*4+3]);
                acc[q*4+0] = fmaf(a1, w1.x, acc[q*4+0]); acc[q*4+1] = fmaf(a1, w1.y, acc[q*4+1]);
                acc[q*4+2] = fmaf(a1, w1.z, acc[q*4+2]); acc[q*4+3] = fmaf(a1, w1.w, acc[q*4+3]);
            }
        }
    }
    int pl = plb + lane;
    int pg = p0 + pl;
    const float* hp = h + (size_t)pg * 64 + dbase;
    const u32* zp = (const u32*)(Z + (size_t)pl * 64 + dbase);
    float* op = out + (size_t)pg * 64 + dbase;
    float o[8];
    #pragma unroll
    for (int j = 0; j < 4; ++j) {
        u32 zw = zp[j];
        float q0 = tanhf(acc[2 * j]);
        float q1 = tanhf(acc[2 * j + 1]);
        float z0 = bflo(zw), z1 = bfhi(zw);
        o[2 * j]     = (1.f - z0) * hp[2 * j]     + z0 * q0;
        o[2 * j + 1] = (1.f - z1) * hp[2 * j + 1] + z1 * q1;
    }
    #pragma unroll
    for (int q4 = 0; q4 < 2; ++q4)
        *(float4*)&op[q4 * 4] = make_float4(o[q4*4], o[q4*4+1], o[q4*4+2], o[q4*4+3]);
}

extern "C" void kernel_launch(void* const* d_in, const int* in_sizes, int n_in,
                              void* d_out, int out_size, void* d_ws, size_t ws_size,
                              hipStream_t stream)
{
    const float* h  = (const float*)d_in[0];
    const float* x  = (const float*)d_in[1];
    // d_in[2] = c (unused by the reference)
    const float* W1 = (const float*)d_in[3];
    const float* b1 = (const float*)d_in[4];
    const float* W2 = (const float*)d_in[5];
    const float* b2 = (const float*)d_in[6];
    const float* W3 = (const float*)d_in[7];
    const float* b3 = (const float*)d_in[8];
    const int* nidx = (const int*)d_in[9];
    const float* ef = (const float*)d_in[10];
    float* out = (float*)d_out;

    char* wsb = (char*)d_ws;
    size_t PN = (ws_size >= 32768ull * 512ull) ? 32768 : 8192;
    int passes = (int)(32768 / PN);

    u32* P01 = (u32*)wsb;                       // [PN][64] u32 (gate-interleaved bf16 pair)
    u16* Y01 = (u16*)(wsb + PN * 256);          // [PN][128] bf16
    u16* Z   = (u16*)wsb;                       // alias (P01 dead after K2)
    u16* RH  = (u16*)(wsb + PN * 128);          // alias P01 upper half
    u16* P2  = Y01;                             // alias (Y01 dead after K3)
    u16* Y2  = (u16*)((char*)Y01 + PN * 128);   // alias Y01 upper half

    for (int s = 0; s < passes; ++s) {
        int p0 = (int)(s * PN);
        dim3 gM((unsigned)(PN / 64));
        dim3 gP((unsigned)(PN / 4));
        k_gemm_p01<<<gM, 512, 0, stream>>>(h, x, W1, b1, P01, p0);
        k_pool01 <<<gP, 256, 0, stream>>>(P01, W1, nidx, ef, Y01, p0);
        k_mlp01  <<<gM, 512, 0, stream>>>(Y01, W2, b2, W3, b3, h, Z, RH, p0);
        k_gemm_p2<<<gM, 512, 0, stream>>>(RH, x, W1, b1, P2, p0);
        k_pool2  <<<gP, 256, 0, stream>>>(P2, W1, nidx, ef, Y2, p0);
        k_mlp2   <<<gM, 512, 0, stream>>>(Y2, W2, b2, W3, b3, h, Z, out, p0);
    }
}

// Round 7
// 212.511 us; speedup vs baseline: 1.8054x; 1.0276x over previous
//
#include <hip/hip_runtime.h>
#include <math.h>

typedef unsigned short u16;
typedef unsigned int u32;

#define KNBR 32

__device__ __forceinline__ float bf2f(u16 u) { return __uint_as_float((u32)u << 16); }
__device__ __forceinline__ float bflo(u32 u) { return __uint_as_float(u << 16); }
__device__ __forceinline__ float bfhi(u32 u) { return __uint_as_float(u & 0xffff0000u); }
__device__ __forceinline__ u16 f2bf(float f) {
    u32 u = __float_as_uint(f);
    return (u16)((u + 0x7fffu + ((u >> 16) & 1u)) >> 16);
}
__device__ __forceinline__ u32 pk2(float a, float b) {
    return (u32)f2bf(a) | ((u32)f2bf(b) << 16);
}
__device__ __forceinline__ float leaky(float v) { return v >= 0.f ? v : 0.1f * v; }
__device__ __forceinline__ float sigm(float v) { return 1.f / (1.f + expf(-v)); }

// W1: [3][131][64] fp32 (g*8384 + c*64 + d), b1: [3][64],
// W2/W3: [3][64][64] (g*4096 + c*64 + d), b2/b3: [3][64].
// P01: u32 rows of 64 (channel d holds pk2(gate0, gate1)).

// ---------------- K1: layer-1 preact, gates 0+1 ----------------
// 128-pt block, 8 waves; wave = 16 pts x 128 ch (both gates).
// Thread tile: 4 pts x 4 ch x 2 gates (32 acc). Weights LDS fp32 (K-halves),
// activations packed-bf16 LDS (per-lane b32).
__global__ __launch_bounds__(512) void k_gemm_p01(
    const float* __restrict__ h, const float* __restrict__ x,
    const float* __restrict__ W1f, const float* __restrict__ b1f,
    u32* __restrict__ P01, int p0)
{
    __shared__ u32 a_lds[128 * 65];
    __shared__ float w_lds[2][64 * 64];
    int t = threadIdx.x;
    int plb = blockIdx.x * 128;
    int pgb = p0 + plb;
    for (int i = 0; i < 16; ++i) {
        int id = t + i * 512;               // 0..8191
        int p = id >> 6, cw = id & 63;
        const float* src = (cw < 32) ? (h + (size_t)(pgb + p) * 64 + cw * 2)
                                     : (x + (size_t)(pgb + p) * 64 + (cw - 32) * 2);
        float2 v = *(const float2*)src;
        a_lds[p * 65 + cw] = pk2(v.x, v.y);
    }
    int lane = t & 63;
    int cg = __builtin_amdgcn_readfirstlane(t >> 6);   // 0..7 (point-16-group)
    int di = lane & 15, pi = lane >> 4;
    int pt0 = cg * 16 + pi * 4;
    int dch = di * 4;
    float acc0[4][4], acc1[4][4];
    float4 bv0 = *(const float4*)&b1f[dch];
    float4 bv1 = *(const float4*)&b1f[64 + dch];
    #pragma unroll
    for (int pp = 0; pp < 4; ++pp) {
        acc0[pp][0] = bv0.x; acc0[pp][1] = bv0.y; acc0[pp][2] = bv0.z; acc0[pp][3] = bv0.w;
        acc1[pp][0] = bv1.x; acc1[pp][1] = bv1.y; acc1[pp][2] = bv1.z; acc1[pp][3] = bv1.w;
    }
    for (int half = 0; half < 2; ++half) {
        __syncthreads();                    // a_lds ready / prior compute done
        for (int i = 0; i < 4; ++i) {       // 2048 float4 of weights (2 gates, 64 rows)
            int id = t + i * 512;
            int g = id >> 10, r = (id >> 4) & 63, d4 = id & 15;
            *(float4*)&w_lds[g][r * 64 + d4 * 4] =
                *(const float4*)(W1f + g * 8384 + (half * 64 + r) * 64 + d4 * 4);
        }
        __syncthreads();
        #pragma unroll 2
        for (int cw = 0; cw < 32; ++cw) {
            u32 aw[4];
            #pragma unroll
            for (int pp = 0; pp < 4; ++pp) aw[pp] = a_lds[(pt0 + pp) * 65 + half * 32 + cw];
            float4 wa0 = *(float4*)&w_lds[0][(2 * cw) * 64 + dch];
            float4 wa1 = *(float4*)&w_lds[0][(2 * cw + 1) * 64 + dch];
            float4 wb0 = *(float4*)&w_lds[1][(2 * cw) * 64 + dch];
            float4 wb1 = *(float4*)&w_lds[1][(2 * cw + 1) * 64 + dch];
            #pragma unroll
            for (int pp = 0; pp < 4; ++pp) {
                float a0 = bflo(aw[pp]), a1 = bfhi(aw[pp]);
                acc0[pp][0] = fmaf(a0, wa0.x, acc0[pp][0]);
                acc0[pp][1] = fmaf(a0, wa0.y, acc0[pp][1]);
                acc0[pp][2] = fmaf(a0, wa0.z, acc0[pp][2]);
                acc0[pp][3] = fmaf(a0, wa0.w, acc0[pp][3]);
                acc0[pp][0] = fmaf(a1, wa1.x, acc0[pp][0]);
                acc0[pp][1] = fmaf(a1, wa1.y, acc0[pp][1]);
                acc0[pp][2] = fmaf(a1, wa1.z, acc0[pp][2]);
                acc0[pp][3] = fmaf(a1, wa1.w, acc0[pp][3]);
                acc1[pp][0] = fmaf(a0, wb0.x, acc1[pp][0]);
                acc1[pp][1] = fmaf(a0, wb0.y, acc1[pp][1]);
                acc1[pp][2] = fmaf(a0, wb0.z, acc1[pp][2]);
                acc1[pp][3] = fmaf(a0, wb0.w, acc1[pp][3]);
                acc1[pp][0] = fmaf(a1, wb1.x, acc1[pp][0]);
                acc1[pp][1] = fmaf(a1, wb1.y, acc1[pp][1]);
                acc1[pp][2] = fmaf(a1, wb1.z, acc1[pp][2]);
                acc1[pp][3] = fmaf(a1, wb1.w, acc1[pp][3]);
            }
        }
    }
    #pragma unroll
    for (int pp = 0; pp < 4; ++pp) {
        u32 o[4];
        #pragma unroll
        for (int j = 0; j < 4; ++j) o[j] = pk2(acc0[pp][j], acc1[pp][j]);
        *(uint4*)(P01 + (size_t)(plb + pt0 + pp) * 64 + dch) = *(uint4*)o;
    }
}

// ---------------- K2: gather + edge-proj + maxpool, gates 0,1 ----------------
__global__ __launch_bounds__(256) void k_pool01(
    const u32* __restrict__ P01, const float* __restrict__ W1f,
    const int* __restrict__ nidx, const float* __restrict__ ef,
    u16* __restrict__ Y01, int p0)
{
    int t = threadIdx.x;
    int l = t & 63;
    int wv = __builtin_amdgcn_readfirstlane(t >> 6);
    int pl = blockIdx.x * 4 + wv;
    int pg = p0 + pl;
    int rbase = ((pg >> 13) << 13) - p0;
    float w00 = W1f[8192 + l], w01 = W1f[8256 + l], w02 = W1f[8320 + l];
    float w10 = W1f[16576 + l], w11 = W1f[16640 + l], w12 = W1f[16704 + l];
    const int* ni = nidx + (size_t)pg * KNBR;
    const float* ep = ef + (size_t)pg * KNBR * 3;
    float m0 = -1e30f, m1 = -1e30f;
    #pragma unroll 16
    for (int k = 0; k < KNBR; ++k) {
        int lr = rbase + ni[k];
        float e0 = ep[k * 3 + 0];
        float e1 = ep[k * 3 + 1];
        float e2 = ep[k * 3 + 2];
        u32 g = P01[(size_t)lr * 64 + l];
        float v0 = bflo(g) + e0 * w00 + e1 * w01 + e2 * w02;
        float v1 = bfhi(g) + e0 * w10 + e1 * w11 + e2 * w12;
        m0 = fmaxf(m0, v0);
        m1 = fmaxf(m1, v1);
    }
    Y01[(size_t)pl * 128 + l]      = f2bf(leaky(m0));
    Y01[(size_t)pl * 128 + 64 + l] = f2bf(leaky(m1));
}

// ---------------- K3: 2-layer MLP gates 0,1 -> Z, RH ----------------
// 128-pt block, 8 waves: wave (g = cg>>2, q = cg&3) = 32 pts x 64 ch of gate g.
// Thread tile: 8 pts x 4 ch.
__global__ __launch_bounds__(512) void k_mlp01(
    const u16* __restrict__ Y01,
    const float* __restrict__ W2f, const float* __restrict__ b2f,
    const float* __restrict__ W3f, const float* __restrict__ b3f,
    const float* __restrict__ h, u16* __restrict__ Z, u16* __restrict__ RH, int p0)
{
    __shared__ u32 a_lds[128 * 65];         // [pt][g*32 + cw]
    __shared__ float w_lds[2][64 * 64];
    int t = threadIdx.x;
    int plb = blockIdx.x * 128;
    const u32* Yw = (const u32*)Y01;
    for (int i = 0; i < 16; ++i) {
        int id = t + i * 512;
        int p = id >> 6, cw = id & 63;
        a_lds[p * 65 + cw] = Yw[(size_t)(plb + p) * 64 + cw];
    }
    for (int i = 0; i < 4; ++i) {           // stage W2 (both gates)
        int id = t + i * 512;
        int g = id >> 10, r = (id >> 4) & 63, d4 = id & 15;
        *(float4*)&w_lds[g][r * 64 + d4 * 4] =
            *(const float4*)(W2f + g * 4096 + r * 64 + d4 * 4);
    }
    __syncthreads();
    int lane = t & 63;
    int cg = __builtin_amdgcn_readfirstlane(t >> 6);
    int g = cg >> 2, q = cg & 3;
    int di = lane & 15, pi = lane >> 4;
    int pt0 = q * 32 + pi * 8;
    int dch = di * 4;
    float acc[8][4];
    {
        float4 bv = *(const float4*)&b2f[g * 64 + dch];
        #pragma unroll
        for (int pp = 0; pp < 8; ++pp) {
            acc[pp][0] = bv.x; acc[pp][1] = bv.y; acc[pp][2] = bv.z; acc[pp][3] = bv.w;
        }
    }
    #pragma unroll 2
    for (int cw = 0; cw < 32; ++cw) {
        u32 aw[8];
        #pragma unroll
        for (int pp = 0; pp < 8; ++pp) aw[pp] = a_lds[(pt0 + pp) * 65 + g * 32 + cw];
        float4 w0 = *(float4*)&w_lds[g][(2 * cw) * 64 + dch];
        float4 w1 = *(float4*)&w_lds[g][(2 * cw + 1) * 64 + dch];
        #pragma unroll
        for (int pp = 0; pp < 8; ++pp) {
            float a0 = bflo(aw[pp]), a1 = bfhi(aw[pp]);
            acc[pp][0] = fmaf(a0, w0.x, acc[pp][0]);
            acc[pp][1] = fmaf(a0, w0.y, acc[pp][1]);
            acc[pp][2] = fmaf(a0, w0.z, acc[pp][2]);
            acc[pp][3] = fmaf(a0, w0.w, acc[pp][3]);
            acc[pp][0] = fmaf(a1, w1.x, acc[pp][0]);
            acc[pp][1] = fmaf(a1, w1.y, acc[pp][1]);
            acc[pp][2] = fmaf(a1, w1.z, acc[pp][2]);
            acc[pp][3] = fmaf(a1, w1.w, acc[pp][3]);
        }
    }
    __syncthreads();                        // layer-1 reads done
    #pragma unroll
    for (int pp = 0; pp < 8; ++pp) {        // t back into a_lds (same slots)
        int base = (pt0 + pp) * 65 + g * 32 + di * 2;
        a_lds[base]     = pk2(leaky(acc[pp][0]), leaky(acc[pp][1]));
        a_lds[base + 1] = pk2(leaky(acc[pp][2]), leaky(acc[pp][3]));
    }
    for (int i = 0; i < 4; ++i) {           // restage W3
        int id = t + i * 512;
        int gg = id >> 10, r = (id >> 4) & 63, d4 = id & 15;
        *(float4*)&w_lds[gg][r * 64 + d4 * 4] =
            *(const float4*)(W3f + gg * 4096 + r * 64 + d4 * 4);
    }
    __syncthreads();
    {
        float4 bv = *(const float4*)&b3f[g * 64 + dch];
        #pragma unroll
        for (int pp = 0; pp < 8; ++pp) {
            acc[pp][0] = bv.x; acc[pp][1] = bv.y; acc[pp][2] = bv.z; acc[pp][3] = bv.w;
        }
    }
    #pragma unroll 2
    for (int cw = 0; cw < 32; ++cw) {
        u32 aw[8];
        #pragma unroll
        for (int pp = 0; pp < 8; ++pp) aw[pp] = a_lds[(pt0 + pp) * 65 + g * 32 + cw];
        float4 w0 = *(float4*)&w_lds[g][(2 * cw) * 64 + dch];
        float4 w1 = *(float4*)&w_lds[g][(2 * cw + 1) * 64 + dch];
        #pragma unroll
        for (int pp = 0; pp < 8; ++pp) {
            float a0 = bflo(aw[pp]), a1 = bfhi(aw[pp]);
            acc[pp][0] = fmaf(a0, w0.x, acc[pp][0]);
            acc[pp][1] = fmaf(a0, w0.y, acc[pp][1]);
            acc[pp][2] = fmaf(a0, w0.z, acc[pp][2]);
            acc[pp][3] = fmaf(a0, w0.w, acc[pp][3]);
            acc[pp][0] = fmaf(a1, w1.x, acc[pp][0]);
            acc[pp][1] = fmaf(a1, w1.y, acc[pp][1]);
            acc[pp][2] = fmaf(a1, w1.z, acc[pp][2]);
            acc[pp][3] = fmaf(a1, w1.w, acc[pp][3]);
        }
    }
    #pragma unroll
    for (int pp = 0; pp < 8; ++pp) {
        int pl = plb + pt0 + pp;
        int pg = p0 + pl;
        if (g == 0) {
            uint2 o;
            o.x = pk2(sigm(acc[pp][0]), sigm(acc[pp][1]));
            o.y = pk2(sigm(acc[pp][2]), sigm(acc[pp][3]));
            *(uint2*)(Z + (size_t)pl * 64 + dch) = o;
        } else {
            float4 hv = *(const float4*)&h[(size_t)pg * 64 + dch];
            uint2 o;
            o.x = pk2(sigm(acc[pp][0]) * hv.x, sigm(acc[pp][1]) * hv.y);
            o.y = pk2(sigm(acc[pp][2]) * hv.z, sigm(acc[pp][3]) * hv.w);
            *(uint2*)(RH + (size_t)pl * 64 + dch) = o;
        }
    }
}

// ---------------- K4: layer-1 preact, gate 2 ----------------
// 128-pt block, 8 waves = 16 pts each x 64 ch. Thread tile: 4 pts x 4 ch.
__global__ __launch_bounds__(512) void k_gemm_p2(
    const u16* __restrict__ RH, const float* __restrict__ x,
    const float* __restrict__ W1f, const float* __restrict__ b1f,
    u16* __restrict__ P2, int p0)
{
    __shared__ u32 a_lds[128 * 65];
    __shared__ float w_lds[64 * 64];
    int t = threadIdx.x;
    int plb = blockIdx.x * 128;
    int pgb = p0 + plb;
    const u32* RHw = (const u32*)RH;
    for (int i = 0; i < 16; ++i) {
        int id = t + i * 512;
        int p = id >> 6, cw = id & 63;
        u32 w;
        if (cw < 32) w = RHw[(size_t)(plb + p) * 32 + cw];
        else {
            float2 v = *(const float2*)(x + (size_t)(pgb + p) * 64 + (cw - 32) * 2);
            w = pk2(v.x, v.y);
        }
        a_lds[p * 65 + cw] = w;
    }
    int lane = t & 63;
    int cg = __builtin_amdgcn_readfirstlane(t >> 6);
    int di = lane & 15, pi = lane >> 4;
    int pt0 = cg * 16 + pi * 4;
    int dch = di * 4;
    float acc[4][4];
    {
        float4 bv = *(const float4*)&b1f[128 + dch];
        #pragma unroll
        for (int pp = 0; pp < 4; ++pp) {
            acc[pp][0] = bv.x; acc[pp][1] = bv.y; acc[pp][2] = bv.z; acc[pp][3] = bv.w;
        }
    }
    for (int half = 0; half < 2; ++half) {
        __syncthreads();
        for (int i = 0; i < 2; ++i) {       // 1024 float4
            int id = t + i * 512;
            int r = (id >> 4) & 63, d4 = id & 15;
            *(float4*)&w_lds[r * 64 + d4 * 4] =
                *(const float4*)(W1f + 2 * 8384 + (half * 64 + r) * 64 + d4 * 4);
        }
        __syncthreads();
        #pragma unroll 2
        for (int cw = 0; cw < 32; ++cw) {
            u32 aw[4];
            #pragma unroll
            for (int pp = 0; pp < 4; ++pp) aw[pp] = a_lds[(pt0 + pp) * 65 + half * 32 + cw];
            float4 w0 = *(float4*)&w_lds[(2 * cw) * 64 + dch];
            float4 w1 = *(float4*)&w_lds[(2 * cw + 1) * 64 + dch];
            #pragma unroll
            for (int pp = 0; pp < 4; ++pp) {
                float a0 = bflo(aw[pp]), a1 = bfhi(aw[pp]);
                acc[pp][0] = fmaf(a0, w0.x, acc[pp][0]);
                acc[pp][1] = fmaf(a0, w0.y, acc[pp][1]);
                acc[pp][2] = fmaf(a0, w0.z, acc[pp][2]);
                acc[pp][3] = fmaf(a0, w0.w, acc[pp][3]);
                acc[pp][0] = fmaf(a1, w1.x, acc[pp][0]);
                acc[pp][1] = fmaf(a1, w1.y, acc[pp][1]);
                acc[pp][2] = fmaf(a1, w1.z, acc[pp][2]);
                acc[pp][3] = fmaf(a1, w1.w, acc[pp][3]);
            }
        }
    }
    #pragma unroll
    for (int pp = 0; pp < 4; ++pp) {
        uint2 o;
        o.x = pk2(acc[pp][0], acc[pp][1]);
        o.y = pk2(acc[pp][2], acc[pp][3]);
        *(uint2*)(P2 + (size_t)(plb + pt0 + pp) * 64 + dch) = o;
    }
}

// ---------------- K5: gather + edge + maxpool, gate 2 ----------------
__global__ __launch_bounds__(256) void k_pool2(
    const u16* __restrict__ P2, const float* __restrict__ W1f,
    const int* __restrict__ nidx, const float* __restrict__ ef,
    u16* __restrict__ Y2, int p0)
{
    int t = threadIdx.x;
    int l = t & 63;
    int wv = __builtin_amdgcn_readfirstlane(t >> 6);
    int pl = blockIdx.x * 4 + wv;
    int pg = p0 + pl;
    int rbase = ((pg >> 13) << 13) - p0;
    const float* W = W1f + 2 * 8384;
    float w0 = W[8192 + l], w1 = W[8256 + l], w2 = W[8320 + l];
    const int* ni = nidx + (size_t)pg * KNBR;
    const float* ep = ef + (size_t)pg * KNBR * 3;
    float m = -1e30f;
    #pragma unroll 16
    for (int k = 0; k < KNBR; ++k) {
        int lr = rbase + ni[k];
        float e0 = ep[k * 3 + 0];
        float e1 = ep[k * 3 + 1];
        float e2 = ep[k * 3 + 2];
        float v = bf2f(P2[(size_t)lr * 64 + l]) + e0 * w0 + e1 * w1 + e2 * w2;
        m = fmaxf(m, v);
    }
    Y2[(size_t)pl * 64 + l] = f2bf(leaky(m));
}

// ---------------- K6: MLP gate 2 -> q = tanh, out = (1-z)*h + z*q ----------------
// 128-pt block, 8 waves = 16 pts each. Thread tile: 4 pts x 4 ch.
__global__ __launch_bounds__(512) void k_mlp2(
    const u16* __restrict__ Y2,
    const float* __restrict__ W2f, const float* __restrict__ b2f,
    const float* __restrict__ W3f, const float* __restrict__ b3f,
    const float* __restrict__ h, const u16* __restrict__ Z,
    float* __restrict__ out, int p0)
{
    __shared__ u32 a_lds[128 * 33];
    __shared__ float w_lds[64 * 64];
    int t = threadIdx.x;
    int plb = blockIdx.x * 128;
    const u32* Yw = (const u32*)Y2;
    for (int i = 0; i < 8; ++i) {
        int id = t + i * 512;               // 0..4095
        int p = id >> 5, cw = id & 31;
        a_lds[p * 33 + cw] = Yw[(size_t)(plb + p) * 32 + cw];
    }
    for (int i = 0; i < 2; ++i) {           // stage W2[2]
        int id = t + i * 512;
        int r = (id >> 4) & 63, d4 = id & 15;
        *(float4*)&w_lds[r * 64 + d4 * 4] =
            *(const float4*)(W2f + 2 * 4096 + r * 64 + d4 * 4);
    }
    __syncthreads();
    int lane = t & 63;
    int cg = __builtin_amdgcn_readfirstlane(t >> 6);
    int di = lane & 15, pi = lane >> 4;
    int pt0 = cg * 16 + pi * 4;
    int dch = di * 4;
    float acc[4][4];
    {
        float4 bv = *(const float4*)&b2f[128 + dch];
        #pragma unroll
        for (int pp = 0; pp < 4; ++pp) {
            acc[pp][0] = bv.x; acc[pp][1] = bv.y; acc[pp][2] = bv.z; acc[pp][3] = bv.w;
        }
    }
    #pragma unroll 2
    for (int cw = 0; cw < 32; ++cw) {
        u32 aw[4];
        #pragma unroll
        for (int pp = 0; pp < 4; ++pp) aw[pp] = a_lds[(pt0 + pp) * 33 + cw];
        float4 w0 = *(float4*)&w_lds[(2 * cw) * 64 + dch];
        float4 w1 = *(float4*)&w_lds[(2 * cw + 1) * 64 + dch];
        #pragma unroll
        for (int pp = 0; pp < 4; ++pp) {
            float a0 = bflo(aw[pp]), a1 = bfhi(aw[pp]);
            acc[pp][0] = fmaf(a0, w0.x, acc[pp][0]);
            acc[pp][1] = fmaf(a0, w0.y, acc[pp][1]);
            acc[pp][2] = fmaf(a0, w0.z, acc[pp][2]);
            acc[pp][3] = fmaf(a0, w0.w, acc[pp][3]);
            acc[pp][0] = fmaf(a1, w1.x, acc[pp][0]);
            acc[pp][1] = fmaf(a1, w1.y, acc[pp][1]);
            acc[pp][2] = fmaf(a1, w1.z, acc[pp][2]);
            acc[pp][3] = fmaf(a1, w1.w, acc[pp][3]);
        }
    }
    __syncthreads();
    #pragma unroll
    for (int pp = 0; pp < 4; ++pp) {
        int base = (pt0 + pp) * 33 + di * 2;
        a_lds[base]     = pk2(leaky(acc[pp][0]), leaky(acc[pp][1]));
        a_lds[base + 1] = pk2(leaky(acc[pp][2]), leaky(acc[pp][3]));
    }
    for (int i = 0; i < 2; ++i) {           // restage W3[2]
        int id = t + i * 512;
        int r = (id >> 4) & 63, d4 = id & 15;
        *(float4*)&w_lds[r * 64 + d4 * 4] =
            *(const float4*)(W3f + 2 * 4096 + r * 64 + d4 * 4);
    }
    __syncthreads();
    {
        float4 bv = *(const float4*)&b3f[128 + dch];
        #pragma unroll
        for (int pp = 0; pp < 4; ++pp) {
            acc[pp][0] = bv.x; acc[pp][1] = bv.y; acc[pp][2] = bv.z; acc[pp][3] = bv.w;
        }
    }
    #pragma unroll 2
    for (int cw = 0; cw < 32; ++cw) {
        u32 aw[4];
        #pragma unroll
        for (int pp = 0; pp < 4; ++pp) aw[pp] = a_lds[(pt0 + pp) * 33 + cw];
        float4 w0 = *(float4*)&w_lds[(2 * cw) * 64 + dch];
        float4 w1 = *(float4*)&w_lds[(2 * cw + 1) * 64 + dch];
        #pragma unroll
        for (int pp = 0; pp < 4; ++pp) {
            float a0 = bflo(aw[pp]), a1 = bfhi(aw[pp]);
            acc[pp][0] = fmaf(a0, w0.x, acc[pp][0]);
            acc[pp][1] = fmaf(a0, w0.y, acc[pp][1]);
            acc[pp][2] = fmaf(a0, w0.z, acc[pp][2]);
            acc[pp][3] = fmaf(a0, w0.w, acc[pp][3]);
            acc[pp][0] = fmaf(a1, w1.x, acc[pp][0]);
            acc[pp][1] = fmaf(a1, w1.y, acc[pp][1]);
            acc[pp][2] = fmaf(a1, w1.z, acc[pp][2]);
            acc[pp][3] = fmaf(a1, w1.w, acc[pp][3]);
        }
    }
    #pragma unroll
    for (int pp = 0; pp < 4; ++pp) {
        int pl = plb + pt0 + pp;
        int pg = p0 + pl;
        float4 hv = *(const float4*)&h[(size_t)pg * 64 + dch];
        uint2 zw = *(const uint2*)(Z + (size_t)pl * 64 + dch);
        float z0 = bflo(zw.x), z1 = bfhi(zw.x), z2 = bflo(zw.y), z3 = bfhi(zw.y);
        float4 o;
        o.x = (1.f - z0) * hv.x + z0 * tanhf(acc[pp][0]);
        o.y = (1.f - z1) * hv.y + z1 * tanhf(acc[pp][1]);
        o.z = (1.f - z2) * hv.z + z2 * tanhf(acc[pp][2]);
        o.w = (1.f - z3) * hv.w + z3 * tanhf(acc[pp][3]);
        *(float4*)&out[(size_t)pg * 64 + dch] = o;
    }
}

extern "C" void kernel_launch(void* const* d_in, const int* in_sizes, int n_in,
                              void* d_out, int out_size, void* d_ws, size_t ws_size,
                              hipStream_t stream)
{
    const float* h  = (const float*)d_in[0];
    const float* x  = (const float*)d_in[1];
    // d_in[2] = c (unused by the reference)
    const float* W1 = (const float*)d_in[3];
    const float* b1 = (const float*)d_in[4];
    const float* W2 = (const float*)d_in[5];
    const float* b2 = (const float*)d_in[6];
    const float* W3 = (const float*)d_in[7];
    const float* b3 = (const float*)d_in[8];
    const int* nidx = (const int*)d_in[9];
    const float* ef = (const float*)d_in[10];
    float* out = (float*)d_out;

    char* wsb = (char*)d_ws;
    size_t PN = (ws_size >= 32768ull * 512ull) ? 32768 : 8192;
    int passes = (int)(32768 / PN);

    u32* P01 = (u32*)wsb;                       // [PN][64] u32 (gate-interleaved bf16 pair)
    u16* Y01 = (u16*)(wsb + PN * 256);          // [PN][128] bf16
    u16* Z   = (u16*)wsb;                       // alias (P01 dead after K2)
    u16* RH  = (u16*)(wsb + PN * 128);          // alias P01 upper half
    u16* P2  = Y01;                             // alias (Y01 dead after K3)
    u16* Y2  = (u16*)((char*)Y01 + PN * 128);   // alias Y01 upper half

    for (int s = 0; s < passes; ++s) {
        int p0 = (int)(s * PN);
        dim3 gM((unsigned)(PN / 128));
        dim3 gP((unsigned)(PN / 4));
        k_gemm_p01<<<gM, 512, 0, stream>>>(h, x, W1, b1, P01, p0);
        k_pool01 <<<gP, 256, 0, stream>>>(P01, W1, nidx, ef, Y01, p0);
        k_mlp01  <<<gM, 512, 0, stream>>>(Y01, W2, b2, W3, b3, h, Z, RH, p0);
        k_gemm_p2<<<gM, 512, 0, stream>>>(RH, x, W1, b1, P2, p0);
        k_pool2  <<<gP, 256, 0, stream>>>(P2, W1, nidx, ef, Y2, p0);
        k_mlp2   <<<gM, 512, 0, stream>>>(Y2, W2, b2, W3, b3, h, Z, out, p0);
    }
}

// Round 8
// 198.806 us; speedup vs baseline: 1.9299x; 1.0689x over previous
//
#include <hip/hip_runtime.h>
#include <math.h>

typedef unsigned short u16;
typedef unsigned int u32;

#define KNBR 32

__device__ __forceinline__ float bf2f(u16 u) { return __uint_as_float((u32)u << 16); }
__device__ __forceinline__ float bflo(u32 u) { return __uint_as_float(u << 16); }
__device__ __forceinline__ float bfhi(u32 u) { return __uint_as_float(u & 0xffff0000u); }
__device__ __forceinline__ u16 f2bf(float f) {
    u32 u = __float_as_uint(f);
    return (u16)((u + 0x7fffu + ((u >> 16) & 1u)) >> 16);
}
__device__ __forceinline__ u32 pk2(float a, float b) {
    return (u32)f2bf(a) | ((u32)f2bf(b) << 16);
}
__device__ __forceinline__ float leaky(float v) { return v >= 0.f ? v : 0.1f * v; }
__device__ __forceinline__ float sigm(float v) { return 1.f / (1.f + expf(-v)); }

// W1: [3][131][64] fp32 (g*8384 + c*64 + d), b1: [3][64],
// W2/W3: [3][64][64] (g*4096 + c*64 + d), b2/b3: [3][64].
// P01: u32 rows of 64 (channel d holds pk2(gate0, gate1)).

// ---------------- K_A: layer-1 preact, gates 0+1 ----------------
// 128-pt block, 8 waves; thread tile 4 pts x 4 ch x 2 gates.
__global__ __launch_bounds__(512) void k_gemm_p01(
    const float* __restrict__ h, const float* __restrict__ x,
    const float* __restrict__ W1f, const float* __restrict__ b1f,
    u32* __restrict__ P01, int p0)
{
    __shared__ u32 a_lds[128 * 65];
    __shared__ float w_lds[2][64 * 64];
    int t = threadIdx.x;
    int plb = blockIdx.x * 128;
    int pgb = p0 + plb;
    for (int i = 0; i < 16; ++i) {
        int id = t + i * 512;               // 0..8191
        int p = id >> 6, cw = id & 63;
        const float* src = (cw < 32) ? (h + (size_t)(pgb + p) * 64 + cw * 2)
                                     : (x + (size_t)(pgb + p) * 64 + (cw - 32) * 2);
        float2 v = *(const float2*)src;
        a_lds[p * 65 + cw] = pk2(v.x, v.y);
    }
    int lane = t & 63;
    int cg = __builtin_amdgcn_readfirstlane(t >> 6);   // 0..7
    int di = lane & 15, pi = lane >> 4;
    int pt0 = cg * 16 + pi * 4;
    int dch = di * 4;
    float acc0[4][4], acc1[4][4];
    float4 bv0 = *(const float4*)&b1f[dch];
    float4 bv1 = *(const float4*)&b1f[64 + dch];
    #pragma unroll
    for (int pp = 0; pp < 4; ++pp) {
        acc0[pp][0] = bv0.x; acc0[pp][1] = bv0.y; acc0[pp][2] = bv0.z; acc0[pp][3] = bv0.w;
        acc1[pp][0] = bv1.x; acc1[pp][1] = bv1.y; acc1[pp][2] = bv1.z; acc1[pp][3] = bv1.w;
    }
    for (int half = 0; half < 2; ++half) {
        __syncthreads();
        for (int i = 0; i < 4; ++i) {
            int id = t + i * 512;
            int g = id >> 10, r = (id >> 4) & 63, d4 = id & 15;
            *(float4*)&w_lds[g][r * 64 + d4 * 4] =
                *(const float4*)(W1f + g * 8384 + (half * 64 + r) * 64 + d4 * 4);
        }
        __syncthreads();
        #pragma unroll 2
        for (int cw = 0; cw < 32; ++cw) {
            u32 aw[4];
            #pragma unroll
            for (int pp = 0; pp < 4; ++pp) aw[pp] = a_lds[(pt0 + pp) * 65 + half * 32 + cw];
            float4 wa0 = *(float4*)&w_lds[0][(2 * cw) * 64 + dch];
            float4 wa1 = *(float4*)&w_lds[0][(2 * cw + 1) * 64 + dch];
            float4 wb0 = *(float4*)&w_lds[1][(2 * cw) * 64 + dch];
            float4 wb1 = *(float4*)&w_lds[1][(2 * cw + 1) * 64 + dch];
            #pragma unroll
            for (int pp = 0; pp < 4; ++pp) {
                float a0 = bflo(aw[pp]), a1 = bfhi(aw[pp]);
                acc0[pp][0] = fmaf(a0, wa0.x, acc0[pp][0]);
                acc0[pp][1] = fmaf(a0, wa0.y, acc0[pp][1]);
                acc0[pp][2] = fmaf(a0, wa0.z, acc0[pp][2]);
                acc0[pp][3] = fmaf(a0, wa0.w, acc0[pp][3]);
                acc0[pp][0] = fmaf(a1, wa1.x, acc0[pp][0]);
                acc0[pp][1] = fmaf(a1, wa1.y, acc0[pp][1]);
                acc0[pp][2] = fmaf(a1, wa1.z, acc0[pp][2]);
                acc0[pp][3] = fmaf(a1, wa1.w, acc0[pp][3]);
                acc1[pp][0] = fmaf(a0, wb0.x, acc1[pp][0]);
                acc1[pp][1] = fmaf(a0, wb0.y, acc1[pp][1]);
                acc1[pp][2] = fmaf(a0, wb0.z, acc1[pp][2]);
                acc1[pp][3] = fmaf(a0, wb0.w, acc1[pp][3]);
                acc1[pp][0] = fmaf(a1, wb1.x, acc1[pp][0]);
                acc1[pp][1] = fmaf(a1, wb1.y, acc1[pp][1]);
                acc1[pp][2] = fmaf(a1, wb1.z, acc1[pp][2]);
                acc1[pp][3] = fmaf(a1, wb1.w, acc1[pp][3]);
            }
        }
    }
    #pragma unroll
    for (int pp = 0; pp < 4; ++pp) {
        u32 o[4];
        #pragma unroll
        for (int j = 0; j < 4; ++j) o[j] = pk2(acc0[pp][j], acc1[pp][j]);
        *(uint4*)(P01 + (size_t)(plb + pt0 + pp) * 64 + dch) = *(uint4*)o;
    }
}

// ---------------- K_B: pool01 + mlp01 + gemm_p2 fused ----------------
// 64-pt block, 512 thr (8 waves). Pool: wave pools 8 pts (lane = channel).
// MLP: wave (g=cg>>2, q=cg&3) = 16 pts of gate g, thread 4 pts x 4 ch.
// gemm_p2: thread 2 pts x 4 ch over K=128 [RH|x].
__global__ __launch_bounds__(512) void k_fuse01(
    const u32* __restrict__ P01, const float* __restrict__ W1f,
    const int* __restrict__ nidx, const float* __restrict__ ef,
    const float* __restrict__ h, const float* __restrict__ x,
    const float* __restrict__ W2f, const float* __restrict__ b2f,
    const float* __restrict__ W3f, const float* __restrict__ b3f,
    const float* __restrict__ b1f,
    u16* __restrict__ Z, u16* __restrict__ P2, int p0)
{
    __shared__ u32 a_lds[64 * 65];
    __shared__ float w_lds[2][64 * 64];
    int t = threadIdx.x;
    int plb = blockIdx.x * 64;
    int lane = t & 63;
    int cg = __builtin_amdgcn_readfirstlane(t >> 6);   // 0..7

    // stage W2 (both gates) — global loads overlap the pool gathers below
    for (int i = 0; i < 4; ++i) {
        int id = t + i * 512;
        int g = id >> 10, r = (id >> 4) & 63, d4 = id & 15;
        *(float4*)&w_lds[g][r * 64 + d4 * 4] =
            *(const float4*)(W2f + g * 4096 + r * 64 + d4 * 4);
    }
    // pool phase
    {
        u16* y16 = (u16*)a_lds;
        float w00 = W1f[8192 + lane], w01 = W1f[8256 + lane], w02 = W1f[8320 + lane];
        float w10 = W1f[16576 + lane], w11 = W1f[16640 + lane], w12 = W1f[16704 + lane];
        for (int pp = 0; pp < 8; ++pp) {
            int lp = cg * 8 + pp;
            int pg = p0 + plb + lp;
            int rbase = ((pg >> 13) << 13) - p0;
            const int* ni = nidx + (size_t)pg * KNBR;
            const float* ep = ef + (size_t)pg * KNBR * 3;
            float m0 = -1e30f, m1 = -1e30f;
            #pragma unroll 16
            for (int k = 0; k < KNBR; ++k) {
                int lr = rbase + ni[k];
                u32 g = P01[(size_t)lr * 64 + lane];
                float e0 = ep[3 * k], e1 = ep[3 * k + 1], e2 = ep[3 * k + 2];
                m0 = fmaxf(m0, bflo(g) + e0 * w00 + e1 * w01 + e2 * w02);
                m1 = fmaxf(m1, bfhi(g) + e0 * w10 + e1 * w11 + e2 * w12);
            }
            y16[lp * 130 + lane]      = f2bf(leaky(m0));
            y16[lp * 130 + 64 + lane] = f2bf(leaky(m1));
        }
    }
    __syncthreads();
    // MLP layer 1
    int g = cg >> 2, q = cg & 3;
    int di = lane & 15, pi = lane >> 4;
    int pt0 = q * 16 + pi * 4;
    int dch = di * 4;
    float acc[4][4];
    {
        float4 bv = *(const float4*)&b2f[g * 64 + dch];
        #pragma unroll
        for (int pp = 0; pp < 4; ++pp) {
            acc[pp][0] = bv.x; acc[pp][1] = bv.y; acc[pp][2] = bv.z; acc[pp][3] = bv.w;
        }
    }
    #pragma unroll 2
    for (int cw = 0; cw < 32; ++cw) {
        u32 aw[4];
        #pragma unroll
        for (int pp = 0; pp < 4; ++pp) aw[pp] = a_lds[(pt0 + pp) * 65 + g * 32 + cw];
        float4 w0 = *(float4*)&w_lds[g][(2 * cw) * 64 + dch];
        float4 w1 = *(float4*)&w_lds[g][(2 * cw + 1) * 64 + dch];
        #pragma unroll
        for (int pp = 0; pp < 4; ++pp) {
            float a0 = bflo(aw[pp]), a1 = bfhi(aw[pp]);
            acc[pp][0] = fmaf(a0, w0.x, acc[pp][0]);
            acc[pp][1] = fmaf(a0, w0.y, acc[pp][1]);
            acc[pp][2] = fmaf(a0, w0.z, acc[pp][2]);
            acc[pp][3] = fmaf(a0, w0.w, acc[pp][3]);
            acc[pp][0] = fmaf(a1, w1.x, acc[pp][0]);
            acc[pp][1] = fmaf(a1, w1.y, acc[pp][1]);
            acc[pp][2] = fmaf(a1, w1.z, acc[pp][2]);
            acc[pp][3] = fmaf(a1, w1.w, acc[pp][3]);
        }
    }
    __syncthreads();
    #pragma unroll
    for (int pp = 0; pp < 4; ++pp) {
        int base = (pt0 + pp) * 65 + g * 32 + di * 2;
        a_lds[base]     = pk2(leaky(acc[pp][0]), leaky(acc[pp][1]));
        a_lds[base + 1] = pk2(leaky(acc[pp][2]), leaky(acc[pp][3]));
    }
    for (int i = 0; i < 4; ++i) {           // restage W3
        int id = t + i * 512;
        int gg = id >> 10, r = (id >> 4) & 63, d4 = id & 15;
        *(float4*)&w_lds[gg][r * 64 + d4 * 4] =
            *(const float4*)(W3f + gg * 4096 + r * 64 + d4 * 4);
    }
    __syncthreads();
    {
        float4 bv = *(const float4*)&b3f[g * 64 + dch];
        #pragma unroll
        for (int pp = 0; pp < 4; ++pp) {
            acc[pp][0] = bv.x; acc[pp][1] = bv.y; acc[pp][2] = bv.z; acc[pp][3] = bv.w;
        }
    }
    #pragma unroll 2
    for (int cw = 0; cw < 32; ++cw) {
        u32 aw[4];
        #pragma unroll
        for (int pp = 0; pp < 4; ++pp) aw[pp] = a_lds[(pt0 + pp) * 65 + g * 32 + cw];
        float4 w0 = *(float4*)&w_lds[g][(2 * cw) * 64 + dch];
        float4 w1 = *(float4*)&w_lds[g][(2 * cw + 1) * 64 + dch];
        #pragma unroll
        for (int pp = 0; pp < 4; ++pp) {
            float a0 = bflo(aw[pp]), a1 = bfhi(aw[pp]);
            acc[pp][0] = fmaf(a0, w0.x, acc[pp][0]);
            acc[pp][1] = fmaf(a0, w0.y, acc[pp][1]);
            acc[pp][2] = fmaf(a0, w0.z, acc[pp][2]);
            acc[pp][3] = fmaf(a0, w0.w, acc[pp][3]);
            acc[pp][0] = fmaf(a1, w1.x, acc[pp][0]);
            acc[pp][1] = fmaf(a1, w1.y, acc[pp][1]);
            acc[pp][2] = fmaf(a1, w1.z, acc[pp][2]);
            acc[pp][3] = fmaf(a1, w1.w, acc[pp][3]);
        }
    }
    __syncthreads();                        // layer-2 reads of a_lds done
    // outputs: Z -> global (gate0); RH -> a_lds words 0..31 (gate1)
    if (g == 0) {
        #pragma unroll
        for (int pp = 0; pp < 4; ++pp) {
            int pl = plb + pt0 + pp;
            uint2 o;
            o.x = pk2(sigm(acc[pp][0]), sigm(acc[pp][1]));
            o.y = pk2(sigm(acc[pp][2]), sigm(acc[pp][3]));
            *(uint2*)(Z + (size_t)pl * 64 + dch) = o;
        }
    } else {
        #pragma unroll
        for (int pp = 0; pp < 4; ++pp) {
            int pg = p0 + plb + pt0 + pp;
            float4 hv = *(const float4*)&h[(size_t)pg * 64 + dch];
            int base = (pt0 + pp) * 65 + di * 2;
            a_lds[base]     = pk2(sigm(acc[pp][0]) * hv.x, sigm(acc[pp][1]) * hv.y);
            a_lds[base + 1] = pk2(sigm(acc[pp][2]) * hv.z, sigm(acc[pp][3]) * hv.w);
        }
    }
    // stage x into a_lds words 32..63; stage W1[2] rows 0..127 into w_lds flat
    for (int i = 0; i < 4; ++i) {
        int id = t + i * 512;               // 0..2047
        int p = id >> 5, cw = id & 31;
        float2 v = *(const float2*)(x + (size_t)(p0 + plb + p) * 64 + cw * 2);
        a_lds[p * 65 + 32 + cw] = pk2(v.x, v.y);
    }
    float* wflat = (float*)w_lds;
    for (int i = 0; i < 4; ++i) {
        int id = t + i * 512;               // 0..2047 float4, 128 rows
        int r = id >> 4, d4 = id & 15;
        *(float4*)&wflat[r * 64 + d4 * 4] =
            *(const float4*)(W1f + 2 * 8384 + r * 64 + d4 * 4);
    }
    __syncthreads();
    // gemm_p2: thread = 2 pts x 4 ch, K = 128
    int pt0b = cg * 8 + pi * 2;
    float pacc[2][4];
    {
        float4 bv = *(const float4*)&b1f[128 + dch];
        #pragma unroll
        for (int pp = 0; pp < 2; ++pp) {
            pacc[pp][0] = bv.x; pacc[pp][1] = bv.y; pacc[pp][2] = bv.z; pacc[pp][3] = bv.w;
        }
    }
    #pragma unroll 2
    for (int cw = 0; cw < 64; ++cw) {
        u32 aw0 = a_lds[(pt0b + 0) * 65 + cw];
        u32 aw1 = a_lds[(pt0b + 1) * 65 + cw];
        float4 w0 = *(float4*)&wflat[(2 * cw) * 64 + dch];
        float4 w1 = *(float4*)&wflat[(2 * cw + 1) * 64 + dch];
        float a00 = bflo(aw0), a01 = bfhi(aw0);
        float a10 = bflo(aw1), a11 = bfhi(aw1);
        pacc[0][0] = fmaf(a00, w0.x, pacc[0][0]); pacc[0][1] = fmaf(a00, w0.y, pacc[0][1]);
        pacc[0][2] = fmaf(a00, w0.z, pacc[0][2]); pacc[0][3] = fmaf(a00, w0.w, pacc[0][3]);
        pacc[0][0] = fmaf(a01, w1.x, pacc[0][0]); pacc[0][1] = fmaf(a01, w1.y, pacc[0][1]);
        pacc[0][2] = fmaf(a01, w1.z, pacc[0][2]); pacc[0][3] = fmaf(a01, w1.w, pacc[0][3]);
        pacc[1][0] = fmaf(a10, w0.x, pacc[1][0]); pacc[1][1] = fmaf(a10, w0.y, pacc[1][1]);
        pacc[1][2] = fmaf(a10, w0.z, pacc[1][2]); pacc[1][3] = fmaf(a10, w0.w, pacc[1][3]);
        pacc[1][0] = fmaf(a11, w1.x, pacc[1][0]); pacc[1][1] = fmaf(a11, w1.y, pacc[1][1]);
        pacc[1][2] = fmaf(a11, w1.z, pacc[1][2]); pacc[1][3] = fmaf(a11, w1.w, pacc[1][3]);
    }
    #pragma unroll
    for (int pp = 0; pp < 2; ++pp) {
        int pl = plb + pt0b + pp;
        uint2 o;
        o.x = pk2(pacc[pp][0], pacc[pp][1]);
        o.y = pk2(pacc[pp][2], pacc[pp][3]);
        *(uint2*)(P2 + (size_t)pl * 64 + dch) = o;
    }
}

// ---------------- K_C: pool2 + mlp2 fused -> out ----------------
// 64-pt block, 512 thr. Pool: wave pools 8 pts. MLP: thread 2 pts x 4 ch.
__global__ __launch_bounds__(512) void k_fuse2(
    const u16* __restrict__ P2, const float* __restrict__ W1f,
    const int* __restrict__ nidx, const float* __restrict__ ef,
    const float* __restrict__ W2f, const float* __restrict__ b2f,
    const float* __restrict__ W3f, const float* __restrict__ b3f,
    const float* __restrict__ h, const u16* __restrict__ Z,
    float* __restrict__ out, int p0)
{
    __shared__ u32 a_lds[64 * 33];
    __shared__ float w_lds[64 * 64];
    int t = threadIdx.x;
    int plb = blockIdx.x * 64;
    int lane = t & 63;
    int cg = __builtin_amdgcn_readfirstlane(t >> 6);
    for (int i = 0; i < 2; ++i) {           // stage W2[2]
        int id = t + i * 512;
        int r = (id >> 4) & 63, d4 = id & 15;
        *(float4*)&w_lds[r * 64 + d4 * 4] =
            *(const float4*)(W2f + 2 * 4096 + r * 64 + d4 * 4);
    }
    {
        const float* W = W1f + 2 * 8384;
        float w0 = W[8192 + lane], w1 = W[8256 + lane], w2 = W[8320 + lane];
        u16* y16 = (u16*)a_lds;
        for (int pp = 0; pp < 8; ++pp) {
            int lp = cg * 8 + pp;
            int pg = p0 + plb + lp;
            int rbase = ((pg >> 13) << 13) - p0;
            const int* ni = nidx + (size_t)pg * KNBR;
            const float* ep = ef + (size_t)pg * KNBR * 3;
            float m = -1e30f;
            #pragma unroll 16
            for (int k = 0; k < KNBR; ++k) {
                int lr = rbase + ni[k];
                float e0 = ep[3 * k], e1 = ep[3 * k + 1], e2 = ep[3 * k + 2];
                float v = bf2f(P2[(size_t)lr * 64 + lane]) + e0 * w0 + e1 * w1 + e2 * w2;
                m = fmaxf(m, v);
            }
            y16[lp * 66 + lane] = f2bf(leaky(m));
        }
    }
    __syncthreads();
    int di = lane & 15, pi = lane >> 4;
    int pt0 = cg * 8 + pi * 2;
    int dch = di * 4;
    float acc[2][4];
    {
        float4 bv = *(const float4*)&b2f[128 + dch];
        #pragma unroll
        for (int pp = 0; pp < 2; ++pp) {
            acc[pp][0] = bv.x; acc[pp][1] = bv.y; acc[pp][2] = bv.z; acc[pp][3] = bv.w;
        }
    }
    #pragma unroll 2
    for (int cw = 0; cw < 32; ++cw) {
        u32 aw0 = a_lds[(pt0 + 0) * 33 + cw];
        u32 aw1 = a_lds[(pt0 + 1) * 33 + cw];
        float4 w0 = *(float4*)&w_lds[(2 * cw) * 64 + dch];
        float4 w1 = *(float4*)&w_lds[(2 * cw + 1) * 64 + dch];
        float a00 = bflo(aw0), a01 = bfhi(aw0);
        float a10 = bflo(aw1), a11 = bfhi(aw1);
        acc[0][0] = fmaf(a00, w0.x, acc[0][0]); acc[0][1] = fmaf(a00, w0.y, acc[0][1]);
        acc[0][2] = fmaf(a00, w0.z, acc[0][2]); acc[0][3] = fmaf(a00, w0.w, acc[0][3]);
        acc[0][0] = fmaf(a01, w1.x, acc[0][0]); acc[0][1] = fmaf(a01, w1.y, acc[0][1]);
        acc[0][2] = fmaf(a01, w1.z, acc[0][2]); acc[0][3] = fmaf(a01, w1.w, acc[0][3]);
        acc[1][0] = fmaf(a10, w0.x, acc[1][0]); acc[1][1] = fmaf(a10, w0.y, acc[1][1]);
        acc[1][2] = fmaf(a10, w0.z, acc[1][2]); acc[1][3] = fmaf(a10, w0.w, acc[1][3]);
        acc[1][0] = fmaf(a11, w1.x, acc[1][0]); acc[1][1] = fmaf(a11, w1.y, acc[1][1]);
        acc[1][2] = fmaf(a11, w1.z, acc[1][2]); acc[1][3] = fmaf(a11, w1.w, acc[1][3]);
    }
    __syncthreads();
    #pragma unroll
    for (int pp = 0; pp < 2; ++pp) {
        int base = (pt0 + pp) * 33 + di * 2;
        a_lds[base]     = pk2(leaky(acc[pp][0]), leaky(acc[pp][1]));
        a_lds[base + 1] = pk2(leaky(acc[pp][2]), leaky(acc[pp][3]));
    }
    for (int i = 0; i < 2; ++i) {           // restage W3[2]
        int id = t + i * 512;
        int r = (id >> 4) & 63, d4 = id & 15;
        *(float4*)&w_lds[r * 64 + d4 * 4] =
            *(const float4*)(W3f + 2 * 4096 + r * 64 + d4 * 4);
    }
    __syncthreads();
    {
        float4 bv = *(const float4*)&b3f[128 + dch];
        #pragma unroll
        for (int pp = 0; pp < 2; ++pp) {
            acc[pp][0] = bv.x; acc[pp][1] = bv.y; acc[pp][2] = bv.z; acc[pp][3] = bv.w;
        }
    }
    #pragma unroll 2
    for (int cw = 0; cw < 32; ++cw) {
        u32 aw0 = a_lds[(pt0 + 0) * 33 + cw];
        u32 aw1 = a_lds[(pt0 + 1) * 33 + cw];
        float4 w0 = *(float4*)&w_lds[(2 * cw) * 64 + dch];
        float4 w1 = *(float4*)&w_lds[(2 * cw + 1) * 64 + dch];
        float a00 = bflo(aw0), a01 = bfhi(aw0);
        float a10 = bflo(aw1), a11 = bfhi(aw1);
        acc[0][0] = fmaf(a00, w0.x, acc[0][0]); acc[0][1] = fmaf(a00, w0.y, acc[0][1]);
        acc[0][2] = fmaf(a00, w0.z, acc[0][2]); acc[0][3] = fmaf(a00, w0.w, acc[0][3]);
        acc[0][0] = fmaf(a01, w1.x, acc[0][0]); acc[0][1] = fmaf(a01, w1.y, acc[0][1]);
        acc[0][2] = fmaf(a01, w1.z, acc[0][2]); acc[0][3] = fmaf(a01, w1.w, acc[0][3]);
        acc[1][0] = fmaf(a10, w0.x, acc[1][0]); acc[1][1] = fmaf(a10, w0.y, acc[1][1]);
        acc[1][2] = fmaf(a10, w0.z, acc[1][2]); acc[1][3] = fmaf(a10, w0.w, acc[1][3]);
        acc[1][0] = fmaf(a11, w1.x, acc[1][0]); acc[1][1] = fmaf(a11, w1.y, acc[1][1]);
        acc[1][2] = fmaf(a11, w1.z, acc[1][2]); acc[1][3] = fmaf(a11, w1.w, acc[1][3]);
    }
    #pragma unroll
    for (int pp = 0; pp < 2; ++pp) {
        int pl = plb + pt0 + pp;
        int pg = p0 + pl;
        float4 hv = *(const float4*)&h[(size_t)pg * 64 + dch];
        uint2 zw = *(const uint2*)(Z + (size_t)pl * 64 + dch);
        float z0 = bflo(zw.x), z1 = bfhi(zw.x), z2 = bflo(zw.y), z3 = bfhi(zw.y);
        float4 o;
        o.x = (1.f - z0) * hv.x + z0 * tanhf(acc[pp][0]);
        o.y = (1.f - z1) * hv.y + z1 * tanhf(acc[pp][1]);
        o.z = (1.f - z2) * hv.z + z2 * tanhf(acc[pp][2]);
        o.w = (1.f - z3) * hv.w + z3 * tanhf(acc[pp][3]);
        *(float4*)&out[(size_t)pg * 64 + dch] = o;
    }
}

extern "C" void kernel_launch(void* const* d_in, const int* in_sizes, int n_in,
                              void* d_out, int out_size, void* d_ws, size_t ws_size,
                              hipStream_t stream)
{
    const float* h  = (const float*)d_in[0];
    const float* x  = (const float*)d_in[1];
    // d_in[2] = c (unused by the reference)
    const float* W1 = (const float*)d_in[3];
    const float* b1 = (const float*)d_in[4];
    const float* W2 = (const float*)d_in[5];
    const float* b2 = (const float*)d_in[6];
    const float* W3 = (const float*)d_in[7];
    const float* b3 = (const float*)d_in[8];
    const int* nidx = (const int*)d_in[9];
    const float* ef = (const float*)d_in[10];
    float* out = (float*)d_out;

    char* wsb = (char*)d_ws;
    size_t PN = (ws_size >= 32768ull * 512ull) ? 32768 : 8192;
    int passes = (int)(32768 / PN);

    u32* P01 = (u32*)wsb;                       // [PN][64] u32 (gate-interleaved bf16 pair)
    u16* Z   = (u16*)(wsb + PN * 256);          // [PN][64] bf16
    u16* P2  = (u16*)(wsb + PN * 384);          // [PN][64] bf16

    for (int s = 0; s < passes; ++s) {
        int p0 = (int)(s * PN);
        k_gemm_p01<<<dim3((unsigned)(PN / 128)), 512, 0, stream>>>(h, x, W1, b1, P01, p0);
        k_fuse01  <<<dim3((unsigned)(PN / 64)),  512, 0, stream>>>(P01, W1, nidx, ef, h, x,
                                                                   W2, b2, W3, b3, b1, Z, P2, p0);
        k_fuse2   <<<dim3((unsigned)(PN / 64)),  512, 0, stream>>>(P2, W1, nidx, ef,
                                                                   W2, b2, W3, b3, h, Z, out, p0);
    }
}